// Round 15
// baseline (140.830 us; speedup 1.0000x reference)
//
#include <hip/hip_runtime.h>
#include <hip/hip_bf16.h>

// Problem constants
#define BATCH 16
#define CH    32      // depthwise group count
#define CIN   64
#define OUTC  64
#define HH    128     // h after stride-2 stem
#define WW    128
#define HW    (HH * WW)
#define MHW   65536   // mas plane 256*256

typedef __attribute__((ext_vector_type(8))) short bf16x8;
typedef __attribute__((ext_vector_type(4))) float f32x4;

__device__ inline unsigned short bf16u(float x) {
  union { __hip_bfloat16 h; unsigned short s; } u;
  u.h = __float2bfloat16(x);
  return u.s;
}
__device__ inline unsigned int pack2(float lo, float hi) {
  return (unsigned int)bf16u(lo) | ((unsigned int)bf16u(hi) << 16);
}
__device__ inline float losf(unsigned u) { return __uint_as_float(u << 16); }
__device__ inline float hisf(unsigned u) { return __uint_as_float(u & 0xffff0000u); }

// ---------------------------------------------------------------------------
// Kernel 0: weight prep (bf16 MFMA A-fragments). Unchanged.
//  - wfrag  [9][2][64][8]: stem w_inp
//  - wfrag2 [4][4][64][8]: final GEMM K=128 (k<64 sq, k>=64 cen)
//  - wfrag3 [9][4][64][8]: folded dout conv W9[tap][o][C]
// ---------------------------------------------------------------------------
__global__ __launch_bounds__(256) void k_prep_weights(
    const float* __restrict__ w_out, const float* __restrict__ w_inp,
    const float* __restrict__ w3,
    unsigned short* __restrict__ wfrag, unsigned short* __restrict__ wfrag2,
    unsigned short* __restrict__ wfrag3) {
  int t = blockIdx.x * 256 + threadIdx.x;
  if (t < 9 * 2 * 64 * 8) {
    int e    = t & 7;
    int lane = (t >> 3) & 63;
    int ct   = (t >> 9) & 1;
    int tap  = t >> 10;
    int co = ct * 16 + (lane & 15);
    int ci = (lane >> 4) * 8 + e;
    wfrag[t] = bf16u(w_inp[(co * CH + ci) * 9 + tap]);
  }
  int t2 = t - 9216;
  if (t2 >= 0 && t2 < 8192) {
    int e    = t2 & 7;
    int lane = (t2 >> 3) & 63;
    int ot   = (t2 >> 9) & 3;
    int kt   = t2 >> 11;
    int o = ot * 16 + (lane & 15);
    int k = kt * 32 + (lane >> 4) * 8 + e;
    int col = (k < 64) ? k : 64 + k;   // sq block 0..63, cen block 128..191
    wfrag2[t2] = bf16u(w_out[o * 192 + col]);
  }
  int t3 = t - 17408;
  if (t3 >= 0 && t3 < 18432) {
    int e    = t3 & 7;
    int lane = (t3 >> 3) & 63;
    int ot   = (t3 >> 9) & 3;
    int tap  = t3 >> 11;
    int o = ot * 16 + (lane & 15);
    int C = (lane >> 4) * 8 + e;
    const int kmap[9] = {0, 1, 2, 7, -1, 3, 6, 5, 4};
    float v = 0.f;
    if (tap == 4) {
      for (int k = 0; k < 8; ++k)
        for (int op = 0; op < 2; ++op)
          v += w_out[o * 192 + 64 + 2 * C + op] * w3[C * 16 + op * 8 + k];
    } else {
      int k = kmap[tap];
      for (int op = 0; op < 2; ++op)
        v -= w_out[o * 192 + 64 + 2 * C + op] * w3[C * 16 + op * 8 + k];
    }
    wfrag3[t3] = bf16u(v);
  }
}

// ---------------------------------------------------------------------------
// Kernel 1 v9 (MERGED transpose+stem): stage the 5-row x 129-col x 32-ch
// window DIRECTLY from planar mas. Staging map: task idx -> (cell, col),
// cell = (r, ci-pair); consecutive lanes -> consecutive cols of one plane-row
// (contiguous 256B+ per wave instr, prep_mas's proven pattern). Pack ci-pair
// to u32, write LDS addr = pix*18 + cp (byte-identical to old 36-short
// layout; 8B-aligned b128 fragment reads). Tile: 2 out-rows x 64 out-cols,
// 4 waves (wave = 16-col subtile, both co-halves). 46.4KB LDS, 3 blocks/CU.
// Batch-matched XCD swizzle (xbuf L2 handoff to k_fused).
// ---------------------------------------------------------------------------
__global__ __launch_bounds__(256, 3) void k_stem(
    const float* __restrict__ mas, const unsigned short* __restrict__ wfrag,
    const float* __restrict__ b_inp, unsigned short* __restrict__ xbuf) {
  __shared__ alignas(16) unsigned int xs32[645 * 18];   // 46.4 KB

  // XCD swizzle: 2048 blocks = 8 XCD x 256; b = F>>7 -> XCD k gets {2k,2k+1}
  const int W = blockIdx.x + 2 * blockIdx.y + 128 * blockIdx.z;
  const int F = (W & 7) * 256 + (W >> 3);
  const int bx = F & 1;          // col half (64 cols)
  const int by = (F >> 1) & 63;  // row band of 2
  const int b  = F >> 7;         // batch

  const int t  = threadIdx.x;
  const int lane = t & 63;
  const int w = t >> 6;

  const int I0 = by * 2, J0 = bx * 64;
  const int R0 = 2 * I0 - 1, C0 = 2 * J0 - 1;

  // A-fragments: both co-halves per wave
  bf16x8 af[9][2];
#pragma unroll
  for (int tap = 0; tap < 9; ++tap)
#pragma unroll
    for (int ct = 0; ct < 2; ++ct)
      af[tap][ct] = ((const bf16x8*)wfrag)[(tap * 2 + ct) * 64 + lane];

  // ---- staging: 80 cells (r 0..4, cp 0..15) x 129 cols, from planar mas ----
  const float* mb = mas + (size_t)b * CH * MHW;
  for (int idx = t; idx < 80 * 129; idx += 256) {
    int cell = idx / 129;
    int col  = idx - cell * 129;
    int r  = cell >> 4;          // 0..4
    int cp = cell & 15;          // ci pair
    int gr = R0 + r, gc = C0 + col;   // gr<=255, gc<=255 by construction
    unsigned v = 0u;
    if (gr >= 0 && gc >= 0) {
      const float* p = mb + (size_t)(2 * cp) * MHW + (size_t)gr * 256 + gc;
      v = pack2(p[0], p[MHW]);
    }
    xs32[(r * 129 + col) * 18 + cp] = v;
  }
  __syncthreads();

  // ---- compute: wave w -> cols [J0+16w, +16), both co-halves, 2 rows ----
  f32x4 acc[2][2];               // [il][ct]
#pragma unroll
  for (int il = 0; il < 2; ++il)
#pragma unroll
    for (int ct = 0; ct < 2; ++ct) acc[il][ct] = 0.f;

  const int jt = w * 16 + (lane & 15);   // tile col 0..63
  const int g4 = (lane >> 4) * 4;        // u32 offset of this ci-group

#pragma unroll
  for (int ky = 0; ky < 3; ++ky) {
#pragma unroll
    for (int kx = 0; kx < 3; ++kx) {
      const int tap = ky * 3 + kx;
#pragma unroll
      for (int il = 0; il < 2; ++il) {
        int pix = (2 * il + ky) * 129 + 2 * jt + kx;
        bf16x8 bfr = *(const bf16x8*)(xs32 + pix * 18 + g4);
        acc[il][0] = __builtin_amdgcn_mfma_f32_16x16x32_bf16(
            af[tap][0], bfr, acc[il][0], 0, 0, 0);
        acc[il][1] = __builtin_amdgcn_mfma_f32_16x16x32_bf16(
            af[tap][1], bfr, acc[il][1], 0, 0, 0);
      }
    }
  }

  // ---- epilogue: bias + SiLU, store bf16 channel-interleaved ----
  float4 bia[2];
  bia[0] = *(const float4*)(b_inp + (lane >> 4) * 4);
  bia[1] = *(const float4*)(b_inp + 16 + (lane >> 4) * 4);
  const int colg = J0 + jt;
#pragma unroll
  for (int il = 0; il < 2; ++il) {
    int i = I0 + il;
#pragma unroll
    for (int ct = 0; ct < 2; ++ct) {
      int co0 = ct * 16 + (lane >> 4) * 4;
      float y0 = acc[il][ct][0] + ((const float*)&bia[ct])[0];
      float y1 = acc[il][ct][1] + ((const float*)&bia[ct])[1];
      float y2 = acc[il][ct][2] + ((const float*)&bia[ct])[2];
      float y3 = acc[il][ct][3] + ((const float*)&bia[ct])[3];
      float s0 = y0 / (1.f + __expf(-y0));
      float s1 = y1 / (1.f + __expf(-y1));
      float s2 = y2 / (1.f + __expf(-y2));
      float s3 = y3 / (1.f + __expf(-y3));
      uint2 uv;
      uv.x = pack2(s0, s1);
      uv.y = pack2(s2, s3);
      *(uint2*)(xbuf + ((size_t)(b * HH + i) * WW + colg) * 32 + co0) = uv;
    }
  }
}

// ---------------------------------------------------------------------------
// Kernel 2 v3 + XCD swizzle (unchanged — proven).
// ---------------------------------------------------------------------------
#define PPITCH 132

__global__ __launch_bounds__(256, 4) void k_fused(
    const unsigned short* __restrict__ xbuf, const float* __restrict__ cen,
    const float* __restrict__ w1, const float* __restrict__ w2,
    const unsigned short* __restrict__ wfrag2,
    const unsigned short* __restrict__ wfrag3,
    const float* __restrict__ b_out, float* __restrict__ out) {
  __shared__ alignas(16) unsigned short xs[196 * 36];      // 14.1 KB
  __shared__ alignas(16) unsigned short panel[64][PPITCH]; // 16.9 KB

  const int W = blockIdx.x + 16 * blockIdx.y + 256 * blockIdx.z;
  const int F = (W & 7) * 512 + (W >> 3);
  const int bx = F & 15;
  const int by = (F >> 4) & 15;
  const int b  = F >> 8;

  const int t  = threadIdx.x;
  const int lane = t & 63;
  const int w = t >> 6;
  const int I0 = by * 8, J0 = bx * 8;

  bf16x8 af3[9], af2[4];
#pragma unroll
  for (int tap = 0; tap < 9; ++tap)
    af3[tap] = ((const bf16x8*)wfrag3)[(tap * 4 + w) * 64 + lane];
#pragma unroll
  for (int kt = 0; kt < 4; ++kt)
    af2[kt] = ((const bf16x8*)wfrag2)[(kt * 4 + w) * 64 + lane];

  // stage cen -> panel cols k=64..127 (2 ch per u32)
#pragma unroll
  for (int j = 0; j < 8; ++j) {
    int idx = j * 256 + t;
    int cc = idx >> 6, p = idx & 63;
    int py = p >> 3, px = p & 7;
    const float* cp = cen + ((size_t)(b * CIN + 2 * cc) * HH + I0 + py) * WW
                      + J0 + px;
    *(unsigned int*)&panel[p][64 + 2 * cc] = pack2(cp[0], cp[HW]);
  }

  // stage xs: 14x14 halo x 32 ch from channel-interleaved xbuf
  {
    int row = t >> 4, col = t & 15;
    if (row < 14 && col < 14) {
      int gi = I0 - 3 + row, gj = J0 - 3 + col;
      bool ok = (gi >= 0 && gi < HH && gj >= 0 && gj < WW);
      const unsigned short* gp = xbuf +
          ((size_t)((size_t)b * HH + (ok ? gi : 0)) * WW + (ok ? gj : 0)) * 32;
      unsigned short* sp = xs + (row * 14 + col) * 36;
#pragma unroll
      for (int s = 0; s < 4; ++s) {
        uint4 v = make_uint4(0u, 0u, 0u, 0u);
        if (ok) v = *(const uint4*)(gp + 8 * s);
        *(uint2*)(sp + 8 * s)     = make_uint2(v.x, v.y);
        *(uint2*)(sp + 8 * s + 4) = make_uint2(v.z, v.w);
      }
    }
  }
  __syncthreads();

  // ---- Phase A: folded-dout 9-tap dilated conv via MFMA ----
  f32x4 acc[4];
#pragma unroll
  for (int pt = 0; pt < 4; ++pt) acc[pt] = 0.f;

  const int prow = lane & 15;
  const int gsh = (lane >> 4) * 8;
#pragma unroll
  for (int pt = 0; pt < 4; ++pt) {
    int p = pt * 16 + prow;
    int ppy = p >> 3, ppx = p & 7;
#pragma unroll
    for (int ty = 0; ty < 3; ++ty)
#pragma unroll
      for (int tx = 0; tx < 3; ++tx) {
        int pos = (ppy + 3 * ty) * 14 + ppx + 3 * tx;
        bf16x8 bfr = *(const bf16x8*)(xs + pos * 36 + gsh);
        acc[pt] = __builtin_amdgcn_mfma_f32_16x16x32_bf16(
            af3[ty * 3 + tx], bfr, acc[pt], 0, 0, 0);
      }
  }

  // ---- Phase B: square gates (VALU), dual-channel tasks ----
  {
    const int py = lane >> 3, px = lane & 7;
    const int posc = (py + 3) * 14 + (px + 3);
    int pos8[8];
    pos8[0] = (py + 0) * 14 + px + 0;   // (-3,-3)
    pos8[1] = (py + 0) * 14 + px + 3;   // (-3, 0)
    pos8[2] = (py + 0) * 14 + px + 6;   // (-3, 3)
    pos8[3] = (py + 3) * 14 + px + 6;   // ( 0, 3)
    pos8[4] = (py + 6) * 14 + px + 6;   // ( 3, 3)
    pos8[5] = (py + 6) * 14 + px + 3;   // ( 3, 0)
    pos8[6] = (py + 6) * 14 + px + 0;   // ( 3,-3)
    pos8[7] = (py + 3) * 14 + px + 0;   // ( 0,-3)

#pragma unroll
    for (int j = 0; j < 4; ++j) {
      int c2 = __builtin_amdgcn_readfirstlane(j * 4 + w);  // 0..15
      const float* w1lo = w1 + (2 * c2) * 16;       // wave-uniform (scalar)
      const float* w1hi = w1 + (2 * c2 + 1) * 16;
      const float* w2lo = w2 + (2 * c2) * 16;
      const float* w2hi = w2 + (2 * c2 + 1) * 16;
      unsigned uc = *(const unsigned*)(xs + posc * 36 + 2 * c2);
      float clo = losf(uc), chi = hisf(uc);
      float g1l0 = 0, g1l1 = 0, g2l0 = 0, g2l1 = 0;
      float g1h0 = 0, g1h1 = 0, g2h0 = 0, g2h1 = 0;
#pragma unroll
      for (int k = 0; k < 8; ++k) {
        unsigned us = *(const unsigned*)(xs + pos8[k] * 36 + 2 * c2);
        float dlo = clo - losf(us);
        float dhi = chi - hisf(us);
        g1l0 += dlo * w1lo[k];  g1l1 += dlo * w1lo[8 + k];
        g2l0 += dlo * w2lo[k];  g2l1 += dlo * w2lo[8 + k];
        g1h0 += dhi * w1hi[k];  g1h1 += dhi * w1hi[8 + k];
        g2h0 += dhi * w2hi[k];  g2h1 += dhi * w2hi[8 + k];
      }
      uint2 wv;
      wv.x = pack2(g1l0 * g2l0, g1l1 * g2l1);
      wv.y = pack2(g1h0 * g2h0, g1h1 * g2h1);
      *(uint2*)&panel[lane][4 * c2] = wv;   // sq cols 4c2..4c2+3
    }
  }
  __syncthreads();

  // ---- Phase C: final GEMM K=128 over panel (sq + cen) ----
#pragma unroll
  for (int pt = 0; pt < 4; ++pt) {
#pragma unroll
    for (int kt = 0; kt < 4; ++kt) {
      bf16x8 bfr = *(const bf16x8*)(&panel[pt * 16 + prow][kt * 32 + gsh]);
      acc[pt] = __builtin_amdgcn_mfma_f32_16x16x32_bf16(
          af2[kt], bfr, acc[pt], 0, 0, 0);
    }
  }

  // epilogue: bias + store fp32
  float4 bo = *(const float4*)(b_out + w * 16 + (lane >> 4) * 4);
#pragma unroll
  for (int pt = 0; pt < 4; ++pt) {
    int p = pt * 16 + prow;
    int ppy = p >> 3, ppx = p & 7;
#pragma unroll
    for (int r = 0; r < 4; ++r) {
      int o = w * 16 + (lane >> 4) * 4 + r;
      out[((b * OUTC + o) * HH + I0 + ppy) * WW + J0 + ppx] =
          acc[pt][r] + ((const float*)&bo)[r];
    }
  }
}

// ---------------------------------------------------------------------------
extern "C" void kernel_launch(void* const* d_in, const int* in_sizes, int n_in,
                              void* d_out, int out_size, void* d_ws, size_t ws_size,
                              hipStream_t stream) {
  const float* cen   = (const float*)d_in[0];
  const float* mas   = (const float*)d_in[1];
  const float* w_inp = (const float*)d_in[2];
  const float* b_inp = (const float*)d_in[3];
  const float* w1    = (const float*)d_in[4];
  const float* w2    = (const float*)d_in[5];
  const float* w3    = (const float*)d_in[6];
  const float* w_out = (const float*)d_in[7];
  const float* b_out = (const float*)d_in[8];
  float* out = (float*)d_out;

  unsigned short* xbuf   = (unsigned short*)d_ws;            // bf16, 16.8 MB
  unsigned short* wfrag  = xbuf + (size_t)BATCH * HW * 32;   // 9216
  unsigned short* wfrag2 = wfrag + 9216;                     // 8192
  unsigned short* wfrag3 = wfrag2 + 8192;                    // 18432

  hipLaunchKernelGGL(k_prep_weights, dim3(140), dim3(256), 0, stream,
                     w_out, w_inp, w3, wfrag, wfrag2, wfrag3);
  hipLaunchKernelGGL(k_stem, dim3(2, 64, 16), dim3(256), 0, stream,
                     mas, wfrag, b_inp, xbuf);
  hipLaunchKernelGGL(k_fused, dim3(16, 16, 16), dim3(256), 0, stream,
                     xbuf, cen, w1, w2, wfrag2, wfrag3, b_out, out);
}

// Round 16
// 120.711 us; speedup vs baseline: 1.1667x; 1.1667x over previous
//
#include <hip/hip_runtime.h>
#include <hip/hip_bf16.h>

// Problem constants
#define BATCH 16
#define CH    32      // depthwise group count
#define CIN   64
#define OUTC  64
#define HH    128     // h after stride-2 stem
#define WW    128
#define HW    (HH * WW)
#define MHW   65536   // mas plane 256*256

typedef __attribute__((ext_vector_type(8))) short bf16x8;
typedef __attribute__((ext_vector_type(4))) float f32x4;

__device__ inline unsigned short bf16u(float x) {
  union { __hip_bfloat16 h; unsigned short s; } u;
  u.h = __float2bfloat16(x);
  return u.s;
}
__device__ inline unsigned int pack2(float lo, float hi) {
  return (unsigned int)bf16u(lo) | ((unsigned int)bf16u(hi) << 16);
}
__device__ inline float losf(unsigned u) { return __uint_as_float(u << 16); }
__device__ inline float hisf(unsigned u) { return __uint_as_float(u & 0xffff0000u); }

// ---------------------------------------------------------------------------
// Kernel 0: weight prep (bf16 MFMA A-fragments). Unchanged.
// ---------------------------------------------------------------------------
__global__ __launch_bounds__(256) void k_prep_weights(
    const float* __restrict__ w_out, const float* __restrict__ w_inp,
    const float* __restrict__ w3,
    unsigned short* __restrict__ wfrag, unsigned short* __restrict__ wfrag2,
    unsigned short* __restrict__ wfrag3) {
  int t = blockIdx.x * 256 + threadIdx.x;
  if (t < 9 * 2 * 64 * 8) {
    int e    = t & 7;
    int lane = (t >> 3) & 63;
    int ct   = (t >> 9) & 1;
    int tap  = t >> 10;
    int co = ct * 16 + (lane & 15);
    int ci = (lane >> 4) * 8 + e;
    wfrag[t] = bf16u(w_inp[(co * CH + ci) * 9 + tap]);
  }
  int t2 = t - 9216;
  if (t2 >= 0 && t2 < 8192) {
    int e    = t2 & 7;
    int lane = (t2 >> 3) & 63;
    int ot   = (t2 >> 9) & 3;
    int kt   = t2 >> 11;
    int o = ot * 16 + (lane & 15);
    int k = kt * 32 + (lane >> 4) * 8 + e;
    int col = (k < 64) ? k : 64 + k;   // sq block 0..63, cen block 128..191
    wfrag2[t2] = bf16u(w_out[o * 192 + col]);
  }
  int t3 = t - 17408;
  if (t3 >= 0 && t3 < 18432) {
    int e    = t3 & 7;
    int lane = (t3 >> 3) & 63;
    int ot   = (t3 >> 9) & 3;
    int tap  = t3 >> 11;
    int o = ot * 16 + (lane & 15);
    int C = (lane >> 4) * 8 + e;
    const int kmap[9] = {0, 1, 2, 7, -1, 3, 6, 5, 4};
    float v = 0.f;
    if (tap == 4) {
      for (int k = 0; k < 8; ++k)
        for (int op = 0; op < 2; ++op)
          v += w_out[o * 192 + 64 + 2 * C + op] * w3[C * 16 + op * 8 + k];
    } else {
      int k = kmap[tap];
      for (int op = 0; op < 2; ++op)
        v -= w_out[o * 192 + 64 + 2 * C + op] * w3[C * 16 + op * 8 + k];
    }
    wfrag3[t3] = bf16u(v);
  }
}

// ---------------------------------------------------------------------------
// Kernel 0b: mas fp32 planar [b][32][256][256] -> masb bf16 channel-
// interleaved [b][256][256][32]. One block per (b,row). v2: each thread
// reads a float2 COLUMN PAIR per plane (512B/wave-instr, half the load
// instructions of v1). Batch-matched XCD swizzle.
// ---------------------------------------------------------------------------
__global__ __launch_bounds__(256) void k_prep_mas(
    const float* __restrict__ mas, unsigned short* __restrict__ masb) {
  __shared__ alignas(16) unsigned short tile[256 * 36];   // 18.4 KB

  const int W = blockIdx.x + 256 * blockIdx.y;   // row + 256*b
  const int F = (W & 7) * 512 + (W >> 3);        // XCD k -> batches {2k,2k+1}
  const int r = F & 255;
  const int b = F >> 8;
  const int t = threadIdx.x;

  const int c0  = (t & 127) * 2;    // column pair
  const int cib = (t >> 7) * 16;    // ci half
  const float* gp = mas + (size_t)b * CH * MHW + (size_t)r * 256 + c0;
#pragma unroll 8
  for (int q = 0; q < 8; ++q) {
    int ci = cib + 2 * q;
    float2 v0 = *(const float2*)(gp + (size_t)ci * MHW);
    float2 v1 = *(const float2*)(gp + (size_t)(ci + 1) * MHW);
    *(unsigned*)&tile[c0 * 36 + ci]       = pack2(v0.x, v1.x);
    *(unsigned*)&tile[(c0 + 1) * 36 + ci] = pack2(v0.y, v1.y);
  }
  __syncthreads();

  unsigned short* op = masb + (((size_t)b * 256 + r) * 256) * 32;
#pragma unroll
  for (int it = 0; it < 4; ++it) {
    int idx = it * 256 + t;
    int px = idx >> 2, seg = idx & 3;
    uint2 a  = *(const uint2*)&tile[px * 36 + seg * 8];
    uint2 bq = *(const uint2*)&tile[px * 36 + seg * 8 + 4];
    *(uint4*)(op + (size_t)px * 32 + seg * 8) = make_uint4(a.x, a.y, bq.x, bq.y);
  }
}

// ---------------------------------------------------------------------------
// Kernel 1 v10: LDS-FREE stem. B-fragments loaded DIRECTLY from channel-
// interleaved masb: lane l -> pixel col (lane&15), bytes [(l>>4)*16, +16).
// A wave's 64 lanes collectively consume 16 pixels x 64B; alternate 64B
// lines are the kx+-1 taps' loads (L1 reuse). No LDS, no barrier ->
// occupancy-driven latency hiding. Per wave: 2 out-rows x 16 out-cols x
// 32 co = 18 A-frag loads (per-tap, L2-hot) + 36 B-frag loads + 36 MFMA.
// Batch-matched XCD swizzle.
// ---------------------------------------------------------------------------
__global__ __launch_bounds__(256, 4) void k_stem(
    const unsigned short* __restrict__ masb,
    const unsigned short* __restrict__ wfrag,
    const float* __restrict__ b_inp, unsigned short* __restrict__ xbuf) {
  // XCD swizzle: 2048 blocks = 8 XCD x 256; b = F>>7 -> XCD k gets {2k,2k+1}
  const int W = blockIdx.x + 2 * blockIdx.y + 128 * blockIdx.z;
  const int F = (W & 7) * 256 + (W >> 3);
  const int bx = F & 1;          // col half (64 cols)
  const int by = (F >> 1) & 63;  // row band of 2
  const int b  = F >> 7;         // batch

  const int t  = threadIdx.x;
  const int lane = t & 63;
  const int w = t >> 6;

  const int I0 = by * 2;
  const int J0 = bx * 64 + w * 16;       // this wave's 16 output cols
  const int jl = lane & 15;
  const int gsh = (lane >> 4) * 8;       // short offset of ci-group

  const unsigned short* mb = masb + (size_t)b * 256 * 256 * 32;
  const bf16x8* wf = (const bf16x8*)wfrag;

  const int grow = 2 * I0 - 1;
  const int gcol = 2 * (J0 + jl) - 1;

  f32x4 acc[2][2];
#pragma unroll
  for (int il = 0; il < 2; ++il)
#pragma unroll
    for (int ct = 0; ct < 2; ++ct) acc[il][ct] = 0.f;

#pragma unroll
  for (int ky = 0; ky < 3; ++ky) {
#pragma unroll
    for (int kx = 0; kx < 3; ++kx) {
      const int tap = ky * 3 + kx;
      bf16x8 a0 = wf[(tap * 2 + 0) * 64 + lane];
      bf16x8 a1 = wf[(tap * 2 + 1) * 64 + lane];
#pragma unroll
      for (int il = 0; il < 2; ++il) {
        int gr = grow + 2 * il + ky;     // <= 255 by construction
        int gc = gcol + kx;              // <= 255 by construction
        bf16x8 bfr = {};
        if (gr >= 0 && gc >= 0)
          bfr = *(const bf16x8*)(mb + ((size_t)gr * 256 + gc) * 32 + gsh);
        acc[il][0] = __builtin_amdgcn_mfma_f32_16x16x32_bf16(
            a0, bfr, acc[il][0], 0, 0, 0);
        acc[il][1] = __builtin_amdgcn_mfma_f32_16x16x32_bf16(
            a1, bfr, acc[il][1], 0, 0, 0);
      }
    }
  }

  // ---- epilogue: bias + SiLU, store bf16 channel-interleaved ----
  float4 bia[2];
  bia[0] = *(const float4*)(b_inp + (lane >> 4) * 4);
  bia[1] = *(const float4*)(b_inp + 16 + (lane >> 4) * 4);
  const int colg = J0 + jl;
#pragma unroll
  for (int il = 0; il < 2; ++il) {
    int i = I0 + il;
#pragma unroll
    for (int ct = 0; ct < 2; ++ct) {
      int co0 = ct * 16 + (lane >> 4) * 4;
      float y0 = acc[il][ct][0] + ((const float*)&bia[ct])[0];
      float y1 = acc[il][ct][1] + ((const float*)&bia[ct])[1];
      float y2 = acc[il][ct][2] + ((const float*)&bia[ct])[2];
      float y3 = acc[il][ct][3] + ((const float*)&bia[ct])[3];
      float s0 = y0 / (1.f + __expf(-y0));
      float s1 = y1 / (1.f + __expf(-y1));
      float s2 = y2 / (1.f + __expf(-y2));
      float s3 = y3 / (1.f + __expf(-y3));
      uint2 uv;
      uv.x = pack2(s0, s1);
      uv.y = pack2(s2, s3);
      *(uint2*)(xbuf + ((size_t)(b * HH + i) * WW + colg) * 32 + co0) = uv;
    }
  }
}

// ---------------------------------------------------------------------------
// Kernel 2 v3 + XCD swizzle (unchanged — proven).
// ---------------------------------------------------------------------------
#define PPITCH 132

__global__ __launch_bounds__(256, 4) void k_fused(
    const unsigned short* __restrict__ xbuf, const float* __restrict__ cen,
    const float* __restrict__ w1, const float* __restrict__ w2,
    const unsigned short* __restrict__ wfrag2,
    const unsigned short* __restrict__ wfrag3,
    const float* __restrict__ b_out, float* __restrict__ out) {
  __shared__ alignas(16) unsigned short xs[196 * 36];      // 14.1 KB
  __shared__ alignas(16) unsigned short panel[64][PPITCH]; // 16.9 KB

  const int W = blockIdx.x + 16 * blockIdx.y + 256 * blockIdx.z;
  const int F = (W & 7) * 512 + (W >> 3);
  const int bx = F & 15;
  const int by = (F >> 4) & 15;
  const int b  = F >> 8;

  const int t  = threadIdx.x;
  const int lane = t & 63;
  const int w = t >> 6;
  const int I0 = by * 8, J0 = bx * 8;

  bf16x8 af3[9], af2[4];
#pragma unroll
  for (int tap = 0; tap < 9; ++tap)
    af3[tap] = ((const bf16x8*)wfrag3)[(tap * 4 + w) * 64 + lane];
#pragma unroll
  for (int kt = 0; kt < 4; ++kt)
    af2[kt] = ((const bf16x8*)wfrag2)[(kt * 4 + w) * 64 + lane];

  // stage cen -> panel cols k=64..127 (2 ch per u32)
#pragma unroll
  for (int j = 0; j < 8; ++j) {
    int idx = j * 256 + t;
    int cc = idx >> 6, p = idx & 63;
    int py = p >> 3, px = p & 7;
    const float* cp = cen + ((size_t)(b * CIN + 2 * cc) * HH + I0 + py) * WW
                      + J0 + px;
    *(unsigned int*)&panel[p][64 + 2 * cc] = pack2(cp[0], cp[HW]);
  }

  // stage xs: 14x14 halo x 32 ch from channel-interleaved xbuf
  {
    int row = t >> 4, col = t & 15;
    if (row < 14 && col < 14) {
      int gi = I0 - 3 + row, gj = J0 - 3 + col;
      bool ok = (gi >= 0 && gi < HH && gj >= 0 && gj < WW);
      const unsigned short* gp = xbuf +
          ((size_t)((size_t)b * HH + (ok ? gi : 0)) * WW + (ok ? gj : 0)) * 32;
      unsigned short* sp = xs + (row * 14 + col) * 36;
#pragma unroll
      for (int s = 0; s < 4; ++s) {
        uint4 v = make_uint4(0u, 0u, 0u, 0u);
        if (ok) v = *(const uint4*)(gp + 8 * s);
        *(uint2*)(sp + 8 * s)     = make_uint2(v.x, v.y);
        *(uint2*)(sp + 8 * s + 4) = make_uint2(v.z, v.w);
      }
    }
  }
  __syncthreads();

  // ---- Phase A: folded-dout 9-tap dilated conv via MFMA ----
  f32x4 acc[4];
#pragma unroll
  for (int pt = 0; pt < 4; ++pt) acc[pt] = 0.f;

  const int prow = lane & 15;
  const int gsh = (lane >> 4) * 8;
#pragma unroll
  for (int pt = 0; pt < 4; ++pt) {
    int p = pt * 16 + prow;
    int ppy = p >> 3, ppx = p & 7;
#pragma unroll
    for (int ty = 0; ty < 3; ++ty)
#pragma unroll
      for (int tx = 0; tx < 3; ++tx) {
        int pos = (ppy + 3 * ty) * 14 + ppx + 3 * tx;
        bf16x8 bfr = *(const bf16x8*)(xs + pos * 36 + gsh);
        acc[pt] = __builtin_amdgcn_mfma_f32_16x16x32_bf16(
            af3[ty * 3 + tx], bfr, acc[pt], 0, 0, 0);
      }
  }

  // ---- Phase B: square gates (VALU), dual-channel tasks ----
  {
    const int py = lane >> 3, px = lane & 7;
    const int posc = (py + 3) * 14 + (px + 3);
    int pos8[8];
    pos8[0] = (py + 0) * 14 + px + 0;   // (-3,-3)
    pos8[1] = (py + 0) * 14 + px + 3;   // (-3, 0)
    pos8[2] = (py + 0) * 14 + px + 6;   // (-3, 3)
    pos8[3] = (py + 3) * 14 + px + 6;   // ( 0, 3)
    pos8[4] = (py + 6) * 14 + px + 6;   // ( 3, 3)
    pos8[5] = (py + 6) * 14 + px + 3;   // ( 3, 0)
    pos8[6] = (py + 6) * 14 + px + 0;   // ( 3,-3)
    pos8[7] = (py + 3) * 14 + px + 0;   // ( 0,-3)

#pragma unroll
    for (int j = 0; j < 4; ++j) {
      int c2 = __builtin_amdgcn_readfirstlane(j * 4 + w);  // 0..15
      const float* w1lo = w1 + (2 * c2) * 16;       // wave-uniform (scalar)
      const float* w1hi = w1 + (2 * c2 + 1) * 16;
      const float* w2lo = w2 + (2 * c2) * 16;
      const float* w2hi = w2 + (2 * c2 + 1) * 16;
      unsigned uc = *(const unsigned*)(xs + posc * 36 + 2 * c2);
      float clo = losf(uc), chi = hisf(uc);
      float g1l0 = 0, g1l1 = 0, g2l0 = 0, g2l1 = 0;
      float g1h0 = 0, g1h1 = 0, g2h0 = 0, g2h1 = 0;
#pragma unroll
      for (int k = 0; k < 8; ++k) {
        unsigned us = *(const unsigned*)(xs + pos8[k] * 36 + 2 * c2);
        float dlo = clo - losf(us);
        float dhi = chi - hisf(us);
        g1l0 += dlo * w1lo[k];  g1l1 += dlo * w1lo[8 + k];
        g2l0 += dlo * w2lo[k];  g2l1 += dlo * w2lo[8 + k];
        g1h0 += dhi * w1hi[k];  g1h1 += dhi * w1hi[8 + k];
        g2h0 += dhi * w2hi[k];  g2h1 += dhi * w2hi[8 + k];
      }
      uint2 wv;
      wv.x = pack2(g1l0 * g2l0, g1l1 * g2l1);
      wv.y = pack2(g1h0 * g2h0, g1h1 * g2h1);
      *(uint2*)&panel[lane][4 * c2] = wv;   // sq cols 4c2..4c2+3
    }
  }
  __syncthreads();

  // ---- Phase C: final GEMM K=128 over panel (sq + cen) ----
#pragma unroll
  for (int pt = 0; pt < 4; ++pt) {
#pragma unroll
    for (int kt = 0; kt < 4; ++kt) {
      bf16x8 bfr = *(const bf16x8*)(&panel[pt * 16 + prow][kt * 32 + gsh]);
      acc[pt] = __builtin_amdgcn_mfma_f32_16x16x32_bf16(
          af2[kt], bfr, acc[pt], 0, 0, 0);
    }
  }

  // epilogue: bias + store fp32
  float4 bo = *(const float4*)(b_out + w * 16 + (lane >> 4) * 4);
#pragma unroll
  for (int pt = 0; pt < 4; ++pt) {
    int p = pt * 16 + prow;
    int ppy = p >> 3, ppx = p & 7;
#pragma unroll
    for (int r = 0; r < 4; ++r) {
      int o = w * 16 + (lane >> 4) * 4 + r;
      out[((b * OUTC + o) * HH + I0 + ppy) * WW + J0 + ppx] =
          acc[pt][r] + ((const float*)&bo)[r];
    }
  }
}

// ---------------------------------------------------------------------------
extern "C" void kernel_launch(void* const* d_in, const int* in_sizes, int n_in,
                              void* d_out, int out_size, void* d_ws, size_t ws_size,
                              hipStream_t stream) {
  const float* cen   = (const float*)d_in[0];
  const float* mas   = (const float*)d_in[1];
  const float* w_inp = (const float*)d_in[2];
  const float* b_inp = (const float*)d_in[3];
  const float* w1    = (const float*)d_in[4];
  const float* w2    = (const float*)d_in[5];
  const float* w3    = (const float*)d_in[6];
  const float* w_out = (const float*)d_in[7];
  const float* b_out = (const float*)d_in[8];
  float* out = (float*)d_out;

  unsigned short* masb   = (unsigned short*)d_ws;                  // 67.1 MB
  unsigned short* xbuf   = masb + (size_t)BATCH * 256 * 256 * 32;  // 16.8 MB
  unsigned short* wfrag  = xbuf + (size_t)BATCH * HW * 32;   // 9216
  unsigned short* wfrag2 = wfrag + 9216;                     // 8192
  unsigned short* wfrag3 = wfrag2 + 8192;                    // 18432

  hipLaunchKernelGGL(k_prep_mas, dim3(256, 16), dim3(256), 0, stream,
                     mas, masb);
  hipLaunchKernelGGL(k_prep_weights, dim3(140), dim3(256), 0, stream,
                     w_out, w_inp, w3, wfrag, wfrag2, wfrag3);
  hipLaunchKernelGGL(k_stem, dim3(2, 64, 16), dim3(256), 0, stream,
                     masb, wfrag, b_inp, xbuf);
  hipLaunchKernelGGL(k_fused, dim3(16, 16, 16), dim3(256), 0, stream,
                     xbuf, cen, w1, w2, wfrag2, wfrag3, b_out, out);
}

// Round 17
// 102.212 us; speedup vs baseline: 1.3778x; 1.1810x over previous
//
#include <hip/hip_runtime.h>
#include <hip/hip_bf16.h>

// Problem constants
#define BATCH 16
#define CH    32      // depthwise group count
#define CIN   64
#define OUTC  64
#define HH    128     // h after stride-2 stem
#define WW    128
#define HW    (HH * WW)
#define MHW   65536   // mas plane 256*256

typedef __attribute__((ext_vector_type(8))) short bf16x8;
typedef __attribute__((ext_vector_type(4))) float f32x4;

__device__ inline unsigned short bf16u(float x) {
  union { __hip_bfloat16 h; unsigned short s; } u;
  u.h = __float2bfloat16(x);
  return u.s;
}
__device__ inline unsigned int pack2(float lo, float hi) {
  return (unsigned int)bf16u(lo) | ((unsigned int)bf16u(hi) << 16);
}
__device__ inline float losf(unsigned u) { return __uint_as_float(u << 16); }
__device__ inline float hisf(unsigned u) { return __uint_as_float(u & 0xffff0000u); }

// ---------------------------------------------------------------------------
// Kernel 0: weight prep (bf16 MFMA A-fragments). Unchanged.
// ---------------------------------------------------------------------------
__global__ __launch_bounds__(256) void k_prep_weights(
    const float* __restrict__ w_out, const float* __restrict__ w_inp,
    const float* __restrict__ w3,
    unsigned short* __restrict__ wfrag, unsigned short* __restrict__ wfrag2,
    unsigned short* __restrict__ wfrag3) {
  int t = blockIdx.x * 256 + threadIdx.x;
  if (t < 9 * 2 * 64 * 8) {
    int e    = t & 7;
    int lane = (t >> 3) & 63;
    int ct   = (t >> 9) & 1;
    int tap  = t >> 10;
    int co = ct * 16 + (lane & 15);
    int ci = (lane >> 4) * 8 + e;
    wfrag[t] = bf16u(w_inp[(co * CH + ci) * 9 + tap]);
  }
  int t2 = t - 9216;
  if (t2 >= 0 && t2 < 8192) {
    int e    = t2 & 7;
    int lane = (t2 >> 3) & 63;
    int ot   = (t2 >> 9) & 3;
    int kt   = t2 >> 11;
    int o = ot * 16 + (lane & 15);
    int k = kt * 32 + (lane >> 4) * 8 + e;
    int col = (k < 64) ? k : 64 + k;   // sq block 0..63, cen block 128..191
    wfrag2[t2] = bf16u(w_out[o * 192 + col]);
  }
  int t3 = t - 17408;
  if (t3 >= 0 && t3 < 18432) {
    int e    = t3 & 7;
    int lane = (t3 >> 3) & 63;
    int ot   = (t3 >> 9) & 3;
    int tap  = t3 >> 11;
    int o = ot * 16 + (lane & 15);
    int C = (lane >> 4) * 8 + e;
    const int kmap[9] = {0, 1, 2, 7, -1, 3, 6, 5, 4};
    float v = 0.f;
    if (tap == 4) {
      for (int k = 0; k < 8; ++k)
        for (int op = 0; op < 2; ++op)
          v += w_out[o * 192 + 64 + 2 * C + op] * w3[C * 16 + op * 8 + k];
    } else {
      int k = kmap[tap];
      for (int op = 0; op < 2; ++op)
        v -= w_out[o * 192 + 64 + 2 * C + op] * w3[C * 16 + op * 8 + k];
    }
    wfrag3[t3] = bf16u(v);
  }
}

// ---------------------------------------------------------------------------
// Kernel 1 v11: SINGLE-PASS stem (planar mas -> LDS transpose -> MFMA) at
// prep_mas-class occupancy. Tile 2 out-rows x 32 out-cols; window 5x65x32ch
// bf16 in LDS (pitch 18 u32 = 23.4 KB -> 6 blocks/CU, 24 waves/CU).
// Staging: 80 cells (r, ci-pair) x 32 ALIGNED float2 col-pairs
// (512B/wave-instr, no division, ~20 independent loads/thread) + col-0 tail.
// Compute: wave = (out-row, col-half); 9 b64-pair B-frag reads + 18 MFMA.
// Batch-matched XCD swizzle (xbuf L2 handoff to k_fused).
// ---------------------------------------------------------------------------
__global__ __launch_bounds__(256, 6) void k_stem(
    const float* __restrict__ mas, const unsigned short* __restrict__ wfrag,
    const float* __restrict__ b_inp, unsigned short* __restrict__ xbuf) {
  __shared__ alignas(16) unsigned int xs32[325 * 18];   // 23.4 KB

  // XCD swizzle: 4096 blocks = 8 XCD x 512; b = F>>8 -> XCD k gets {2k,2k+1}
  const int W = blockIdx.x + 4 * blockIdx.y + 256 * blockIdx.z;
  const int F = (W & 7) * 512 + (W >> 3);
  const int bx = F & 3;          // col tile of 32
  const int by = (F >> 2) & 63;  // row band of 2
  const int b  = F >> 8;         // batch

  const int t  = threadIdx.x;
  const int lane = t & 63;
  const int w = t >> 6;

  const int I0 = by * 2, J0 = bx * 32;
  const int R0 = 4 * by - 1, C0 = 64 * bx - 1;

  const float* mb = mas + (size_t)b * CH * MHW;

  // ---- staging: 2560 tasks = 80 cells x 32 aligned float2 pairs ----
#pragma unroll 5
  for (int idx = t; idx < 2560; idx += 256) {
    int cell = idx >> 5;         // r*16 + cp
    int k    = idx & 31;         // col pair -> cols 1+2k, 2+2k
    int r  = cell >> 4;
    int cp = cell & 15;
    int gr = R0 + r;
    unsigned v0 = 0u, v1 = 0u;
    if (gr >= 0) {               // gc = C0+1+2k = 64bx+2k: even, in-bounds
      const float* p = mb + (size_t)(2 * cp) * MHW + (size_t)gr * 256 +
                       (C0 + 1 + 2 * k);
      float2 a = *(const float2*)(p);
      float2 c = *(const float2*)(p + MHW);
      v0 = pack2(a.x, c.x);
      v1 = pack2(a.y, c.y);
    }
    int base = (r * 65 + 1 + 2 * k) * 18 + cp;
    xs32[base]      = v0;
    xs32[base + 18] = v1;
  }
  // tail: col 0 (gc = 64bx-1; invalid only for bx==0)
  if (t < 80) {
    int r = t >> 4, cp = t & 15;
    int gr = R0 + r;
    unsigned v = 0u;
    if (gr >= 0 && bx > 0) {
      const float* p = mb + (size_t)(2 * cp) * MHW + (size_t)gr * 256 + C0;
      v = pack2(p[0], p[MHW]);
    }
    xs32[(r * 65) * 18 + cp] = v;
  }
  __syncthreads();

  // ---- compute: wave (il = w>>1, h = w&1) -> 16 px x 32 co x 9 taps ----
  const int il = w >> 1, h = w & 1;
  const int jl = lane & 15;
  const int g4 = (lane >> 4) * 4;
  const int tc = h * 16 + jl;          // tile col 0..31

  f32x4 acc[2];
  acc[0] = 0.f;
  acc[1] = 0.f;

  const bf16x8* wf = (const bf16x8*)wfrag;
#pragma unroll
  for (int ky = 0; ky < 3; ++ky) {
#pragma unroll
    for (int kx = 0; kx < 3; ++kx) {
      const int tap = ky * 3 + kx;
      bf16x8 a0 = wf[(tap * 2 + 0) * 64 + lane];
      bf16x8 a1 = wf[(tap * 2 + 1) * 64 + lane];
      int pix = (2 * il + ky) * 65 + 2 * tc + kx;
      bf16x8 bfr = *(const bf16x8*)(xs32 + pix * 18 + g4);
      acc[0] = __builtin_amdgcn_mfma_f32_16x16x32_bf16(a0, bfr, acc[0], 0, 0, 0);
      acc[1] = __builtin_amdgcn_mfma_f32_16x16x32_bf16(a1, bfr, acc[1], 0, 0, 0);
    }
  }

  // ---- epilogue: bias + SiLU, store bf16 channel-interleaved ----
  float4 bia[2];
  bia[0] = *(const float4*)(b_inp + (lane >> 4) * 4);
  bia[1] = *(const float4*)(b_inp + 16 + (lane >> 4) * 4);
  const int colg = J0 + tc;
  const int i = I0 + il;
#pragma unroll
  for (int ct = 0; ct < 2; ++ct) {
    int co0 = ct * 16 + (lane >> 4) * 4;
    float y0 = acc[ct][0] + ((const float*)&bia[ct])[0];
    float y1 = acc[ct][1] + ((const float*)&bia[ct])[1];
    float y2 = acc[ct][2] + ((const float*)&bia[ct])[2];
    float y3 = acc[ct][3] + ((const float*)&bia[ct])[3];
    float s0 = y0 / (1.f + __expf(-y0));
    float s1 = y1 / (1.f + __expf(-y1));
    float s2 = y2 / (1.f + __expf(-y2));
    float s3 = y3 / (1.f + __expf(-y3));
    uint2 uv;
    uv.x = pack2(s0, s1);
    uv.y = pack2(s2, s3);
    *(uint2*)(xbuf + ((size_t)(b * HH + i) * WW + colg) * 32 + co0) = uv;
  }
}

// ---------------------------------------------------------------------------
// Kernel 2 v3 + XCD swizzle (unchanged — proven).
// ---------------------------------------------------------------------------
#define PPITCH 132

__global__ __launch_bounds__(256, 4) void k_fused(
    const unsigned short* __restrict__ xbuf, const float* __restrict__ cen,
    const float* __restrict__ w1, const float* __restrict__ w2,
    const unsigned short* __restrict__ wfrag2,
    const unsigned short* __restrict__ wfrag3,
    const float* __restrict__ b_out, float* __restrict__ out) {
  __shared__ alignas(16) unsigned short xs[196 * 36];      // 14.1 KB
  __shared__ alignas(16) unsigned short panel[64][PPITCH]; // 16.9 KB

  const int W = blockIdx.x + 16 * blockIdx.y + 256 * blockIdx.z;
  const int F = (W & 7) * 512 + (W >> 3);
  const int bx = F & 15;
  const int by = (F >> 4) & 15;
  const int b  = F >> 8;

  const int t  = threadIdx.x;
  const int lane = t & 63;
  const int w = t >> 6;
  const int I0 = by * 8, J0 = bx * 8;

  bf16x8 af3[9], af2[4];
#pragma unroll
  for (int tap = 0; tap < 9; ++tap)
    af3[tap] = ((const bf16x8*)wfrag3)[(tap * 4 + w) * 64 + lane];
#pragma unroll
  for (int kt = 0; kt < 4; ++kt)
    af2[kt] = ((const bf16x8*)wfrag2)[(kt * 4 + w) * 64 + lane];

  // stage cen -> panel cols k=64..127 (2 ch per u32)
#pragma unroll
  for (int j = 0; j < 8; ++j) {
    int idx = j * 256 + t;
    int cc = idx >> 6, p = idx & 63;
    int py = p >> 3, px = p & 7;
    const float* cp = cen + ((size_t)(b * CIN + 2 * cc) * HH + I0 + py) * WW
                      + J0 + px;
    *(unsigned int*)&panel[p][64 + 2 * cc] = pack2(cp[0], cp[HW]);
  }

  // stage xs: 14x14 halo x 32 ch from channel-interleaved xbuf
  {
    int row = t >> 4, col = t & 15;
    if (row < 14 && col < 14) {
      int gi = I0 - 3 + row, gj = J0 - 3 + col;
      bool ok = (gi >= 0 && gi < HH && gj >= 0 && gj < WW);
      const unsigned short* gp = xbuf +
          ((size_t)((size_t)b * HH + (ok ? gi : 0)) * WW + (ok ? gj : 0)) * 32;
      unsigned short* sp = xs + (row * 14 + col) * 36;
#pragma unroll
      for (int s = 0; s < 4; ++s) {
        uint4 v = make_uint4(0u, 0u, 0u, 0u);
        if (ok) v = *(const uint4*)(gp + 8 * s);
        *(uint2*)(sp + 8 * s)     = make_uint2(v.x, v.y);
        *(uint2*)(sp + 8 * s + 4) = make_uint2(v.z, v.w);
      }
    }
  }
  __syncthreads();

  // ---- Phase A: folded-dout 9-tap dilated conv via MFMA ----
  f32x4 acc[4];
#pragma unroll
  for (int pt = 0; pt < 4; ++pt) acc[pt] = 0.f;

  const int prow = lane & 15;
  const int gsh = (lane >> 4) * 8;
#pragma unroll
  for (int pt = 0; pt < 4; ++pt) {
    int p = pt * 16 + prow;
    int ppy = p >> 3, ppx = p & 7;
#pragma unroll
    for (int ty = 0; ty < 3; ++ty)
#pragma unroll
      for (int tx = 0; tx < 3; ++tx) {
        int pos = (ppy + 3 * ty) * 14 + ppx + 3 * tx;
        bf16x8 bfr = *(const bf16x8*)(xs + pos * 36 + gsh);
        acc[pt] = __builtin_amdgcn_mfma_f32_16x16x32_bf16(
            af3[ty * 3 + tx], bfr, acc[pt], 0, 0, 0);
      }
  }

  // ---- Phase B: square gates (VALU), dual-channel tasks ----
  {
    const int py = lane >> 3, px = lane & 7;
    const int posc = (py + 3) * 14 + (px + 3);
    int pos8[8];
    pos8[0] = (py + 0) * 14 + px + 0;   // (-3,-3)
    pos8[1] = (py + 0) * 14 + px + 3;   // (-3, 0)
    pos8[2] = (py + 0) * 14 + px + 6;   // (-3, 3)
    pos8[3] = (py + 3) * 14 + px + 6;   // ( 0, 3)
    pos8[4] = (py + 6) * 14 + px + 6;   // ( 3, 3)
    pos8[5] = (py + 6) * 14 + px + 3;   // ( 3, 0)
    pos8[6] = (py + 6) * 14 + px + 0;   // ( 3,-3)
    pos8[7] = (py + 3) * 14 + px + 0;   // ( 0,-3)

#pragma unroll
    for (int j = 0; j < 4; ++j) {
      int c2 = __builtin_amdgcn_readfirstlane(j * 4 + w);  // 0..15
      const float* w1lo = w1 + (2 * c2) * 16;       // wave-uniform (scalar)
      const float* w1hi = w1 + (2 * c2 + 1) * 16;
      const float* w2lo = w2 + (2 * c2) * 16;
      const float* w2hi = w2 + (2 * c2 + 1) * 16;
      unsigned uc = *(const unsigned*)(xs + posc * 36 + 2 * c2);
      float clo = losf(uc), chi = hisf(uc);
      float g1l0 = 0, g1l1 = 0, g2l0 = 0, g2l1 = 0;
      float g1h0 = 0, g1h1 = 0, g2h0 = 0, g2h1 = 0;
#pragma unroll
      for (int k = 0; k < 8; ++k) {
        unsigned us = *(const unsigned*)(xs + pos8[k] * 36 + 2 * c2);
        float dlo = clo - losf(us);
        float dhi = chi - hisf(us);
        g1l0 += dlo * w1lo[k];  g1l1 += dlo * w1lo[8 + k];
        g2l0 += dlo * w2lo[k];  g2l1 += dlo * w2lo[8 + k];
        g1h0 += dhi * w1hi[k];  g1h1 += dhi * w1hi[8 + k];
        g2h0 += dhi * w2hi[k];  g2h1 += dhi * w2hi[8 + k];
      }
      uint2 wv;
      wv.x = pack2(g1l0 * g2l0, g1l1 * g2l1);
      wv.y = pack2(g1h0 * g2h0, g1h1 * g2h1);
      *(uint2*)&panel[lane][4 * c2] = wv;   // sq cols 4c2..4c2+3
    }
  }
  __syncthreads();

  // ---- Phase C: final GEMM K=128 over panel (sq + cen) ----
#pragma unroll
  for (int pt = 0; pt < 4; ++pt) {
#pragma unroll
    for (int kt = 0; kt < 4; ++kt) {
      bf16x8 bfr = *(const bf16x8*)(&panel[pt * 16 + prow][kt * 32 + gsh]);
      acc[pt] = __builtin_amdgcn_mfma_f32_16x16x32_bf16(
          af2[kt], bfr, acc[pt], 0, 0, 0);
    }
  }

  // epilogue: bias + store fp32
  float4 bo = *(const float4*)(b_out + w * 16 + (lane >> 4) * 4);
#pragma unroll
  for (int pt = 0; pt < 4; ++pt) {
    int p = pt * 16 + prow;
    int ppy = p >> 3, ppx = p & 7;
#pragma unroll
    for (int r = 0; r < 4; ++r) {
      int o = w * 16 + (lane >> 4) * 4 + r;
      out[((b * OUTC + o) * HH + I0 + ppy) * WW + J0 + ppx] =
          acc[pt][r] + ((const float*)&bo)[r];
    }
  }
}

// ---------------------------------------------------------------------------
extern "C" void kernel_launch(void* const* d_in, const int* in_sizes, int n_in,
                              void* d_out, int out_size, void* d_ws, size_t ws_size,
                              hipStream_t stream) {
  const float* cen   = (const float*)d_in[0];
  const float* mas   = (const float*)d_in[1];
  const float* w_inp = (const float*)d_in[2];
  const float* b_inp = (const float*)d_in[3];
  const float* w1    = (const float*)d_in[4];
  const float* w2    = (const float*)d_in[5];
  const float* w3    = (const float*)d_in[6];
  const float* w_out = (const float*)d_in[7];
  const float* b_out = (const float*)d_in[8];
  float* out = (float*)d_out;

  unsigned short* xbuf   = (unsigned short*)d_ws;            // bf16, 16.8 MB
  unsigned short* wfrag  = xbuf + (size_t)BATCH * HW * 32;   // 9216
  unsigned short* wfrag2 = wfrag + 9216;                     // 8192
  unsigned short* wfrag3 = wfrag2 + 8192;                    // 18432

  hipLaunchKernelGGL(k_prep_weights, dim3(140), dim3(256), 0, stream,
                     w_out, w_inp, w3, wfrag, wfrag2, wfrag3);
  hipLaunchKernelGGL(k_stem, dim3(4, 64, 16), dim3(256), 0, stream,
                     mas, wfrag, b_inp, xbuf);
  hipLaunchKernelGGL(k_fused, dim3(16, 16, 16), dim3(256), 0, stream,
                     xbuf, cen, w1, w2, wfrag2, wfrag3, b_out, out);
}

// Round 18
// 99.001 us; speedup vs baseline: 1.4225x; 1.0324x over previous
//
#include <hip/hip_runtime.h>
#include <hip/hip_bf16.h>

// Problem constants
#define BATCH 16
#define CH    32      // depthwise group count
#define CIN   64
#define OUTC  64
#define HH    128     // h after stride-2 stem
#define WW    128
#define HW    (HH * WW)
#define MHW   65536   // mas plane 256*256

typedef __attribute__((ext_vector_type(8))) short bf16x8;
typedef __attribute__((ext_vector_type(4))) float f32x4;

__device__ inline unsigned short bf16u(float x) {
  union { __hip_bfloat16 h; unsigned short s; } u;
  u.h = __float2bfloat16(x);
  return u.s;
}
__device__ inline unsigned int pack2(float lo, float hi) {
  return (unsigned int)bf16u(lo) | ((unsigned int)bf16u(hi) << 16);
}
__device__ inline float losf(unsigned u) { return __uint_as_float(u << 16); }
__device__ inline float hisf(unsigned u) { return __uint_as_float(u & 0xffff0000u); }

// ---------------------------------------------------------------------------
// Kernel 0: weight prep (bf16 MFMA A-fragments). Unchanged.
// ---------------------------------------------------------------------------
__global__ __launch_bounds__(256) void k_prep_weights(
    const float* __restrict__ w_out, const float* __restrict__ w_inp,
    const float* __restrict__ w3,
    unsigned short* __restrict__ wfrag, unsigned short* __restrict__ wfrag2,
    unsigned short* __restrict__ wfrag3) {
  int t = blockIdx.x * 256 + threadIdx.x;
  if (t < 9 * 2 * 64 * 8) {
    int e    = t & 7;
    int lane = (t >> 3) & 63;
    int ct   = (t >> 9) & 1;
    int tap  = t >> 10;
    int co = ct * 16 + (lane & 15);
    int ci = (lane >> 4) * 8 + e;
    wfrag[t] = bf16u(w_inp[(co * CH + ci) * 9 + tap]);
  }
  int t2 = t - 9216;
  if (t2 >= 0 && t2 < 8192) {
    int e    = t2 & 7;
    int lane = (t2 >> 3) & 63;
    int ot   = (t2 >> 9) & 3;
    int kt   = t2 >> 11;
    int o = ot * 16 + (lane & 15);
    int k = kt * 32 + (lane >> 4) * 8 + e;
    int col = (k < 64) ? k : 64 + k;   // sq block 0..63, cen block 128..191
    wfrag2[t2] = bf16u(w_out[o * 192 + col]);
  }
  int t3 = t - 17408;
  if (t3 >= 0 && t3 < 18432) {
    int e    = t3 & 7;
    int lane = (t3 >> 3) & 63;
    int ot   = (t3 >> 9) & 3;
    int tap  = t3 >> 11;
    int o = ot * 16 + (lane & 15);
    int C = (lane >> 4) * 8 + e;
    const int kmap[9] = {0, 1, 2, 7, -1, 3, 6, 5, 4};
    float v = 0.f;
    if (tap == 4) {
      for (int k = 0; k < 8; ++k)
        for (int op = 0; op < 2; ++op)
          v += w_out[o * 192 + 64 + 2 * C + op] * w3[C * 16 + op * 8 + k];
    } else {
      int k = kmap[tap];
      for (int op = 0; op < 2; ++op)
        v -= w_out[o * 192 + 64 + 2 * C + op] * w3[C * 16 + op * 8 + k];
    }
    wfrag3[t3] = bf16u(v);
  }
}

// ---------------------------------------------------------------------------
// Kernel 1 v12: single-pass stem (R17 structure) + hoisted boundary guard:
// 63/64 blocks (by>=1) take the unguarded staging fast path.
// ---------------------------------------------------------------------------
__global__ __launch_bounds__(256, 6) void k_stem(
    const float* __restrict__ mas, const unsigned short* __restrict__ wfrag,
    const float* __restrict__ b_inp, unsigned short* __restrict__ xbuf) {
  __shared__ alignas(16) unsigned int xs32[325 * 18];   // 23.4 KB

  // XCD swizzle: 4096 blocks = 8 XCD x 512; b = F>>8 -> XCD k gets {2k,2k+1}
  const int W = blockIdx.x + 4 * blockIdx.y + 256 * blockIdx.z;
  const int F = (W & 7) * 512 + (W >> 3);
  const int bx = F & 3;          // col tile of 32
  const int by = (F >> 2) & 63;  // row band of 2
  const int b  = F >> 8;         // batch

  const int t  = threadIdx.x;
  const int lane = t & 63;
  const int w = t >> 6;

  const int I0 = by * 2, J0 = bx * 32;
  const int R0 = 4 * by - 1, C0 = 64 * bx - 1;

  const float* mb = mas + (size_t)b * CH * MHW;

  // ---- staging: 2560 tasks = 80 cells x 32 aligned float2 pairs ----
  if (R0 >= 0) {                 // fast path: all rows valid (by >= 1)
#pragma unroll 5
    for (int idx = t; idx < 2560; idx += 256) {
      int cell = idx >> 5;
      int k    = idx & 31;
      int r  = cell >> 4;
      int cp = cell & 15;
      const float* p = mb + (size_t)(2 * cp) * MHW +
                       (size_t)(R0 + r) * 256 + (C0 + 1 + 2 * k);
      float2 a = *(const float2*)(p);
      float2 c = *(const float2*)(p + MHW);
      int base = (r * 65 + 1 + 2 * k) * 18 + cp;
      xs32[base]      = pack2(a.x, c.x);
      xs32[base + 18] = pack2(a.y, c.y);
    }
  } else {
#pragma unroll 5
    for (int idx = t; idx < 2560; idx += 256) {
      int cell = idx >> 5;
      int k    = idx & 31;
      int r  = cell >> 4;
      int cp = cell & 15;
      int gr = R0 + r;
      unsigned v0 = 0u, v1 = 0u;
      if (gr >= 0) {
        const float* p = mb + (size_t)(2 * cp) * MHW + (size_t)gr * 256 +
                         (C0 + 1 + 2 * k);
        float2 a = *(const float2*)(p);
        float2 c = *(const float2*)(p + MHW);
        v0 = pack2(a.x, c.x);
        v1 = pack2(a.y, c.y);
      }
      int base = (r * 65 + 1 + 2 * k) * 18 + cp;
      xs32[base]      = v0;
      xs32[base + 18] = v1;
    }
  }
  // tail: col 0 (gc = 64bx-1; invalid only for bx==0)
  if (t < 80) {
    int r = t >> 4, cp = t & 15;
    int gr = R0 + r;
    unsigned v = 0u;
    if (gr >= 0 && bx > 0) {
      const float* p = mb + (size_t)(2 * cp) * MHW + (size_t)gr * 256 + C0;
      v = pack2(p[0], p[MHW]);
    }
    xs32[(r * 65) * 18 + cp] = v;
  }
  __syncthreads();

  // ---- compute: wave (il = w>>1, h = w&1) -> 16 px x 32 co x 9 taps ----
  const int il = w >> 1, h = w & 1;
  const int jl = lane & 15;
  const int g4 = (lane >> 4) * 4;
  const int tc = h * 16 + jl;          // tile col 0..31

  f32x4 acc[2];
  acc[0] = 0.f;
  acc[1] = 0.f;

  const bf16x8* wf = (const bf16x8*)wfrag;
#pragma unroll
  for (int ky = 0; ky < 3; ++ky) {
#pragma unroll
    for (int kx = 0; kx < 3; ++kx) {
      const int tap = ky * 3 + kx;
      bf16x8 a0 = wf[(tap * 2 + 0) * 64 + lane];
      bf16x8 a1 = wf[(tap * 2 + 1) * 64 + lane];
      int pix = (2 * il + ky) * 65 + 2 * tc + kx;
      bf16x8 bfr = *(const bf16x8*)(xs32 + pix * 18 + g4);
      acc[0] = __builtin_amdgcn_mfma_f32_16x16x32_bf16(a0, bfr, acc[0], 0, 0, 0);
      acc[1] = __builtin_amdgcn_mfma_f32_16x16x32_bf16(a1, bfr, acc[1], 0, 0, 0);
    }
  }

  // ---- epilogue: bias + SiLU, store bf16 channel-interleaved ----
  float4 bia[2];
  bia[0] = *(const float4*)(b_inp + (lane >> 4) * 4);
  bia[1] = *(const float4*)(b_inp + 16 + (lane >> 4) * 4);
  const int colg = J0 + tc;
  const int i = I0 + il;
#pragma unroll
  for (int ct = 0; ct < 2; ++ct) {
    int co0 = ct * 16 + (lane >> 4) * 4;
    float y0 = acc[ct][0] + ((const float*)&bia[ct])[0];
    float y1 = acc[ct][1] + ((const float*)&bia[ct])[1];
    float y2 = acc[ct][2] + ((const float*)&bia[ct])[2];
    float y3 = acc[ct][3] + ((const float*)&bia[ct])[3];
    float s0 = y0 / (1.f + __expf(-y0));
    float s1 = y1 / (1.f + __expf(-y1));
    float s2 = y2 / (1.f + __expf(-y2));
    float s3 = y3 / (1.f + __expf(-y3));
    uint2 uv;
    uv.x = pack2(s0, s1);
    uv.y = pack2(s2, s3);
    *(uint2*)(xbuf + ((size_t)(b * HH + i) * WW + colg) * 32 + co0) = uv;
  }
}

// ---------------------------------------------------------------------------
// Kernel 2 v4: fused (proven R17 structure) + float2 cen staging (pixel
// pairs, 8B/lane) + hoisted halo guard (interior blocks unguarded).
// ---------------------------------------------------------------------------
#define PPITCH 132

__global__ __launch_bounds__(256, 4) void k_fused(
    const unsigned short* __restrict__ xbuf, const float* __restrict__ cen,
    const float* __restrict__ w1, const float* __restrict__ w2,
    const unsigned short* __restrict__ wfrag2,
    const unsigned short* __restrict__ wfrag3,
    const float* __restrict__ b_out, float* __restrict__ out) {
  __shared__ alignas(16) unsigned short xs[196 * 36];      // 14.1 KB
  __shared__ alignas(16) unsigned short panel[64][PPITCH]; // 16.9 KB

  const int W = blockIdx.x + 16 * blockIdx.y + 256 * blockIdx.z;
  const int F = (W & 7) * 512 + (W >> 3);
  const int bx = F & 15;
  const int by = (F >> 4) & 15;
  const int b  = F >> 8;

  const int t  = threadIdx.x;
  const int lane = t & 63;
  const int w = t >> 6;
  const int I0 = by * 8, J0 = bx * 8;

  bf16x8 af3[9], af2[4];
#pragma unroll
  for (int tap = 0; tap < 9; ++tap)
    af3[tap] = ((const bf16x8*)wfrag3)[(tap * 4 + w) * 64 + lane];
#pragma unroll
  for (int kt = 0; kt < 4; ++kt)
    af2[kt] = ((const bf16x8*)wfrag2)[(kt * 4 + w) * 64 + lane];

  // stage cen -> panel cols k=64..127: pixel-pair float2 loads (8B/lane)
#pragma unroll
  for (int j = 0; j < 4; ++j) {
    int idx = j * 256 + t;          // 1024 tasks
    int cc = idx >> 5;              // cen channel pair 0..31
    int pp = idx & 31;              // pixel pair 0..31
    int p0 = 2 * pp;
    int py = p0 >> 3, px = p0 & 7;
    const float* cp = cen + ((size_t)(b * CIN + 2 * cc) * HH + I0 + py) * WW
                      + J0 + px;
    float2 a = *(const float2*)(cp);        // ch 2cc, two px
    float2 c = *(const float2*)(cp + HW);   // ch 2cc+1
    *(unsigned int*)&panel[p0][64 + 2 * cc]     = pack2(a.x, c.x);
    *(unsigned int*)&panel[p0 + 1][64 + 2 * cc] = pack2(a.y, c.y);
  }

  // stage xs: 14x14 halo x 32 ch; interior blocks take the unguarded path
  {
    int row = t >> 4, col = t & 15;
    if (row < 14 && col < 14) {
      const bool interior = (bx >= 1 && bx <= 14 && by >= 1 && by <= 14);
      int gi = I0 - 3 + row, gj = J0 - 3 + col;
      unsigned short* sp = xs + (row * 14 + col) * 36;
      if (interior) {
        const unsigned short* gp = xbuf +
            ((size_t)((size_t)b * HH + gi) * WW + gj) * 32;
#pragma unroll
        for (int s = 0; s < 4; ++s) {
          uint4 v = *(const uint4*)(gp + 8 * s);
          *(uint2*)(sp + 8 * s)     = make_uint2(v.x, v.y);
          *(uint2*)(sp + 8 * s + 4) = make_uint2(v.z, v.w);
        }
      } else {
        bool ok = (gi >= 0 && gi < HH && gj >= 0 && gj < WW);
        const unsigned short* gp = xbuf +
            ((size_t)((size_t)b * HH + (ok ? gi : 0)) * WW + (ok ? gj : 0)) * 32;
#pragma unroll
        for (int s = 0; s < 4; ++s) {
          uint4 v = make_uint4(0u, 0u, 0u, 0u);
          if (ok) v = *(const uint4*)(gp + 8 * s);
          *(uint2*)(sp + 8 * s)     = make_uint2(v.x, v.y);
          *(uint2*)(sp + 8 * s + 4) = make_uint2(v.z, v.w);
        }
      }
    }
  }
  __syncthreads();

  // ---- Phase A: folded-dout 9-tap dilated conv via MFMA ----
  f32x4 acc[4];
#pragma unroll
  for (int pt = 0; pt < 4; ++pt) acc[pt] = 0.f;

  const int prow = lane & 15;
  const int gsh = (lane >> 4) * 8;
#pragma unroll
  for (int pt = 0; pt < 4; ++pt) {
    int p = pt * 16 + prow;
    int ppy = p >> 3, ppx = p & 7;
#pragma unroll
    for (int ty = 0; ty < 3; ++ty)
#pragma unroll
      for (int tx = 0; tx < 3; ++tx) {
        int pos = (ppy + 3 * ty) * 14 + ppx + 3 * tx;
        bf16x8 bfr = *(const bf16x8*)(xs + pos * 36 + gsh);
        acc[pt] = __builtin_amdgcn_mfma_f32_16x16x32_bf16(
            af3[ty * 3 + tx], bfr, acc[pt], 0, 0, 0);
      }
  }

  // ---- Phase B: square gates (VALU), dual-channel tasks ----
  {
    const int py = lane >> 3, px = lane & 7;
    const int posc = (py + 3) * 14 + (px + 3);
    int pos8[8];
    pos8[0] = (py + 0) * 14 + px + 0;   // (-3,-3)
    pos8[1] = (py + 0) * 14 + px + 3;   // (-3, 0)
    pos8[2] = (py + 0) * 14 + px + 6;   // (-3, 3)
    pos8[3] = (py + 3) * 14 + px + 6;   // ( 0, 3)
    pos8[4] = (py + 6) * 14 + px + 6;   // ( 3, 3)
    pos8[5] = (py + 6) * 14 + px + 3;   // ( 3, 0)
    pos8[6] = (py + 6) * 14 + px + 0;   // ( 3,-3)
    pos8[7] = (py + 3) * 14 + px + 0;   // ( 0,-3)

#pragma unroll
    for (int j = 0; j < 4; ++j) {
      int c2 = __builtin_amdgcn_readfirstlane(j * 4 + w);  // 0..15
      const float* w1lo = w1 + (2 * c2) * 16;       // wave-uniform (scalar)
      const float* w1hi = w1 + (2 * c2 + 1) * 16;
      const float* w2lo = w2 + (2 * c2) * 16;
      const float* w2hi = w2 + (2 * c2 + 1) * 16;
      unsigned uc = *(const unsigned*)(xs + posc * 36 + 2 * c2);
      float clo = losf(uc), chi = hisf(uc);
      float g1l0 = 0, g1l1 = 0, g2l0 = 0, g2l1 = 0;
      float g1h0 = 0, g1h1 = 0, g2h0 = 0, g2h1 = 0;
#pragma unroll
      for (int k = 0; k < 8; ++k) {
        unsigned us = *(const unsigned*)(xs + pos8[k] * 36 + 2 * c2);
        float dlo = clo - losf(us);
        float dhi = chi - hisf(us);
        g1l0 += dlo * w1lo[k];  g1l1 += dlo * w1lo[8 + k];
        g2l0 += dlo * w2lo[k];  g2l1 += dlo * w2lo[8 + k];
        g1h0 += dhi * w1hi[k];  g1h1 += dhi * w1hi[8 + k];
        g2h0 += dhi * w2hi[k];  g2h1 += dhi * w2hi[8 + k];
      }
      uint2 wv;
      wv.x = pack2(g1l0 * g2l0, g1l1 * g2l1);
      wv.y = pack2(g1h0 * g2h0, g1h1 * g2h1);
      *(uint2*)&panel[lane][4 * c2] = wv;   // sq cols 4c2..4c2+3
    }
  }
  __syncthreads();

  // ---- Phase C: final GEMM K=128 over panel (sq + cen) ----
#pragma unroll
  for (int pt = 0; pt < 4; ++pt) {
#pragma unroll
    for (int kt = 0; kt < 4; ++kt) {
      bf16x8 bfr = *(const bf16x8*)(&panel[pt * 16 + prow][kt * 32 + gsh]);
      acc[pt] = __builtin_amdgcn_mfma_f32_16x16x32_bf16(
          af2[kt], bfr, acc[pt], 0, 0, 0);
    }
  }

  // epilogue: bias + store fp32
  float4 bo = *(const float4*)(b_out + w * 16 + (lane >> 4) * 4);
#pragma unroll
  for (int pt = 0; pt < 4; ++pt) {
    int p = pt * 16 + prow;
    int ppy = p >> 3, ppx = p & 7;
#pragma unroll
    for (int r = 0; r < 4; ++r) {
      int o = w * 16 + (lane >> 4) * 4 + r;
      out[((b * OUTC + o) * HH + I0 + ppy) * WW + J0 + ppx] =
          acc[pt][r] + ((const float*)&bo)[r];
    }
  }
}

// ---------------------------------------------------------------------------
extern "C" void kernel_launch(void* const* d_in, const int* in_sizes, int n_in,
                              void* d_out, int out_size, void* d_ws, size_t ws_size,
                              hipStream_t stream) {
  const float* cen   = (const float*)d_in[0];
  const float* mas   = (const float*)d_in[1];
  const float* w_inp = (const float*)d_in[2];
  const float* b_inp = (const float*)d_in[3];
  const float* w1    = (const float*)d_in[4];
  const float* w2    = (const float*)d_in[5];
  const float* w3    = (const float*)d_in[6];
  const float* w_out = (const float*)d_in[7];
  const float* b_out = (const float*)d_in[8];
  float* out = (float*)d_out;

  unsigned short* xbuf   = (unsigned short*)d_ws;            // bf16, 16.8 MB
  unsigned short* wfrag  = xbuf + (size_t)BATCH * HW * 32;   // 9216
  unsigned short* wfrag2 = wfrag + 9216;                     // 8192
  unsigned short* wfrag3 = wfrag2 + 8192;                    // 18432

  hipLaunchKernelGGL(k_prep_weights, dim3(140), dim3(256), 0, stream,
                     w_out, w_inp, w3, wfrag, wfrag2, wfrag3);
  hipLaunchKernelGGL(k_stem, dim3(4, 64, 16), dim3(256), 0, stream,
                     mas, wfrag, b_inp, xbuf);
  hipLaunchKernelGGL(k_fused, dim3(16, 16, 16), dim3(256), 0, stream,
                     xbuf, cen, w1, w2, wfrag2, wfrag3, b_out, out);
}

// Round 19
// 96.498 us; speedup vs baseline: 1.4594x; 1.0259x over previous
//
#include <hip/hip_runtime.h>
#include <hip/hip_bf16.h>

// Problem constants
#define BATCH 16
#define CH    32      // depthwise group count
#define CIN   64
#define OUTC  64
#define HH    128     // h after stride-2 stem
#define WW    128
#define HW    (HH * WW)
#define MHW   65536   // mas plane 256*256

typedef __attribute__((ext_vector_type(8))) short bf16x8;
typedef __attribute__((ext_vector_type(4))) float f32x4;

__device__ inline unsigned short bf16u(float x) {
  union { __hip_bfloat16 h; unsigned short s; } u;
  u.h = __float2bfloat16(x);
  return u.s;
}
__device__ inline unsigned int pack2(float lo, float hi) {
  return (unsigned int)bf16u(lo) | ((unsigned int)bf16u(hi) << 16);
}
__device__ inline float losf(unsigned u) { return __uint_as_float(u << 16); }
__device__ inline float hisf(unsigned u) { return __uint_as_float(u & 0xffff0000u); }

// ---------------------------------------------------------------------------
// Kernel 0: weight prep (bf16 MFMA A-fragments). Unchanged.
// ---------------------------------------------------------------------------
__global__ __launch_bounds__(256) void k_prep_weights(
    const float* __restrict__ w_out, const float* __restrict__ w_inp,
    const float* __restrict__ w3,
    unsigned short* __restrict__ wfrag, unsigned short* __restrict__ wfrag2,
    unsigned short* __restrict__ wfrag3) {
  int t = blockIdx.x * 256 + threadIdx.x;
  if (t < 9 * 2 * 64 * 8) {
    int e    = t & 7;
    int lane = (t >> 3) & 63;
    int ct   = (t >> 9) & 1;
    int tap  = t >> 10;
    int co = ct * 16 + (lane & 15);
    int ci = (lane >> 4) * 8 + e;
    wfrag[t] = bf16u(w_inp[(co * CH + ci) * 9 + tap]);
  }
  int t2 = t - 9216;
  if (t2 >= 0 && t2 < 8192) {
    int e    = t2 & 7;
    int lane = (t2 >> 3) & 63;
    int ot   = (t2 >> 9) & 3;
    int kt   = t2 >> 11;
    int o = ot * 16 + (lane & 15);
    int k = kt * 32 + (lane >> 4) * 8 + e;
    int col = (k < 64) ? k : 64 + k;   // sq block 0..63, cen block 128..191
    wfrag2[t2] = bf16u(w_out[o * 192 + col]);
  }
  int t3 = t - 17408;
  if (t3 >= 0 && t3 < 18432) {
    int e    = t3 & 7;
    int lane = (t3 >> 3) & 63;
    int ot   = (t3 >> 9) & 3;
    int tap  = t3 >> 11;
    int o = ot * 16 + (lane & 15);
    int C = (lane >> 4) * 8 + e;
    const int kmap[9] = {0, 1, 2, 7, -1, 3, 6, 5, 4};
    float v = 0.f;
    if (tap == 4) {
      for (int k = 0; k < 8; ++k)
        for (int op = 0; op < 2; ++op)
          v += w_out[o * 192 + 64 + 2 * C + op] * w3[C * 16 + op * 8 + k];
    } else {
      int k = kmap[tap];
      for (int op = 0; op < 2; ++op)
        v -= w_out[o * 192 + 64 + 2 * C + op] * w3[C * 16 + op * 8 + k];
    }
    wfrag3[t3] = bf16u(v);
  }
}

// ---------------------------------------------------------------------------
// Kernel 1 v13: single-pass stem (R18 structure), staging fully unrolled.
// ---------------------------------------------------------------------------
__global__ __launch_bounds__(256, 6) void k_stem(
    const float* __restrict__ mas, const unsigned short* __restrict__ wfrag,
    const float* __restrict__ b_inp, unsigned short* __restrict__ xbuf) {
  __shared__ alignas(16) unsigned int xs32[325 * 18];   // 23.4 KB

  // XCD swizzle: 4096 blocks = 8 XCD x 512; b = F>>8 -> XCD k gets {2k,2k+1}
  const int W = blockIdx.x + 4 * blockIdx.y + 256 * blockIdx.z;
  const int F = (W & 7) * 512 + (W >> 3);
  const int bx = F & 3;          // col tile of 32
  const int by = (F >> 2) & 63;  // row band of 2
  const int b  = F >> 8;         // batch

  const int t  = threadIdx.x;
  const int lane = t & 63;
  const int w = t >> 6;

  const int I0 = by * 2, J0 = bx * 32;
  const int R0 = 4 * by - 1, C0 = 64 * bx - 1;

  const float* mb = mas + (size_t)b * CH * MHW;

  // ---- staging: 2560 tasks = 80 cells x 32 aligned float2 pairs ----
  if (R0 >= 0) {                 // fast path: all rows valid (by >= 1)
#pragma unroll 10
    for (int idx = t; idx < 2560; idx += 256) {
      int cell = idx >> 5;
      int k    = idx & 31;
      int r  = cell >> 4;
      int cp = cell & 15;
      const float* p = mb + (size_t)(2 * cp) * MHW +
                       (size_t)(R0 + r) * 256 + (C0 + 1 + 2 * k);
      float2 a = *(const float2*)(p);
      float2 c = *(const float2*)(p + MHW);
      int base = (r * 65 + 1 + 2 * k) * 18 + cp;
      xs32[base]      = pack2(a.x, c.x);
      xs32[base + 18] = pack2(a.y, c.y);
    }
  } else {
#pragma unroll 10
    for (int idx = t; idx < 2560; idx += 256) {
      int cell = idx >> 5;
      int k    = idx & 31;
      int r  = cell >> 4;
      int cp = cell & 15;
      int gr = R0 + r;
      unsigned v0 = 0u, v1 = 0u;
      if (gr >= 0) {
        const float* p = mb + (size_t)(2 * cp) * MHW + (size_t)gr * 256 +
                         (C0 + 1 + 2 * k);
        float2 a = *(const float2*)(p);
        float2 c = *(const float2*)(p + MHW);
        v0 = pack2(a.x, c.x);
        v1 = pack2(a.y, c.y);
      }
      int base = (r * 65 + 1 + 2 * k) * 18 + cp;
      xs32[base]      = v0;
      xs32[base + 18] = v1;
    }
  }
  // tail: col 0 (gc = 64bx-1; invalid only for bx==0)
  if (t < 80) {
    int r = t >> 4, cp = t & 15;
    int gr = R0 + r;
    unsigned v = 0u;
    if (gr >= 0 && bx > 0) {
      const float* p = mb + (size_t)(2 * cp) * MHW + (size_t)gr * 256 + C0;
      v = pack2(p[0], p[MHW]);
    }
    xs32[(r * 65) * 18 + cp] = v;
  }
  __syncthreads();

  // ---- compute: wave (il = w>>1, h = w&1) -> 16 px x 32 co x 9 taps ----
  const int il = w >> 1, h = w & 1;
  const int jl = lane & 15;
  const int g4 = (lane >> 4) * 4;
  const int tc = h * 16 + jl;          // tile col 0..31

  f32x4 acc[2];
  acc[0] = 0.f;
  acc[1] = 0.f;

  const bf16x8* wf = (const bf16x8*)wfrag;
#pragma unroll
  for (int ky = 0; ky < 3; ++ky) {
#pragma unroll
    for (int kx = 0; kx < 3; ++kx) {
      const int tap = ky * 3 + kx;
      bf16x8 a0 = wf[(tap * 2 + 0) * 64 + lane];
      bf16x8 a1 = wf[(tap * 2 + 1) * 64 + lane];
      int pix = (2 * il + ky) * 65 + 2 * tc + kx;
      bf16x8 bfr = *(const bf16x8*)(xs32 + pix * 18 + g4);
      acc[0] = __builtin_amdgcn_mfma_f32_16x16x32_bf16(a0, bfr, acc[0], 0, 0, 0);
      acc[1] = __builtin_amdgcn_mfma_f32_16x16x32_bf16(a1, bfr, acc[1], 0, 0, 0);
    }
  }

  // ---- epilogue: bias + SiLU, store bf16 channel-interleaved ----
  float4 bia[2];
  bia[0] = *(const float4*)(b_inp + (lane >> 4) * 4);
  bia[1] = *(const float4*)(b_inp + 16 + (lane >> 4) * 4);
  const int colg = J0 + tc;
  const int i = I0 + il;
#pragma unroll
  for (int ct = 0; ct < 2; ++ct) {
    int co0 = ct * 16 + (lane >> 4) * 4;
    float y0 = acc[ct][0] + ((const float*)&bia[ct])[0];
    float y1 = acc[ct][1] + ((const float*)&bia[ct])[1];
    float y2 = acc[ct][2] + ((const float*)&bia[ct])[2];
    float y3 = acc[ct][3] + ((const float*)&bia[ct])[3];
    float s0 = y0 / (1.f + __expf(-y0));
    float s1 = y1 / (1.f + __expf(-y1));
    float s2 = y2 / (1.f + __expf(-y2));
    float s3 = y3 / (1.f + __expf(-y3));
    uint2 uv;
    uv.x = pack2(s0, s1);
    uv.y = pack2(s2, s3);
    *(uint2*)(xbuf + ((size_t)(b * HH + i) * WW + colg) * 32 + co0) = uv;
  }
}

// ---------------------------------------------------------------------------
// Kernel 2 v5: fused with 4x16 tile (was 8x8). Output rows are 16 px x 4B =
// full 64B lines per store (kills partial-line write RMW). cen staged via
// aligned float4 row-quads. Halo 10x22 (pitch 36 shorts). Pixel id = lane
// (py = lane>>4, px = lane&15). Panel/MFMA geometry unchanged.
// ---------------------------------------------------------------------------
#define PPITCH 132
#define HALOP 22

__global__ __launch_bounds__(256, 4) void k_fused(
    const unsigned short* __restrict__ xbuf, const float* __restrict__ cen,
    const float* __restrict__ w1, const float* __restrict__ w2,
    const unsigned short* __restrict__ wfrag2,
    const unsigned short* __restrict__ wfrag3,
    const float* __restrict__ b_out, float* __restrict__ out) {
  __shared__ alignas(16) unsigned short xs[220 * 36];      // 15.5 KB
  __shared__ alignas(16) unsigned short panel[64][PPITCH]; // 16.9 KB

  // XCD swizzle: 4096 blocks = 8 XCD x 512; b = F>>8
  const int W = blockIdx.x + 8 * blockIdx.y + 256 * blockIdx.z;
  const int F = (W & 7) * 512 + (W >> 3);
  const int bx = F & 7;          // x tile of 16
  const int by = (F >> 3) & 31;  // y tile of 4
  const int b  = F >> 8;

  const int t  = threadIdx.x;
  const int lane = t & 63;
  const int w = t >> 6;
  const int I0 = by * 4, J0 = bx * 16;

  bf16x8 af3[9], af2[4];
#pragma unroll
  for (int tap = 0; tap < 9; ++tap)
    af3[tap] = ((const bf16x8*)wfrag3)[(tap * 4 + w) * 64 + lane];
#pragma unroll
  for (int kt = 0; kt < 4; ++kt)
    af2[kt] = ((const bf16x8*)wfrag2)[(kt * 4 + w) * 64 + lane];

  // stage cen -> panel cols k=64..127: aligned float4 row-quads
#pragma unroll
  for (int j = 0; j < 2; ++j) {
    int idx = j * 256 + t;          // 512 tasks
    int cc = idx >> 4;              // cen channel pair 0..31
    int q  = idx & 15;              // pixel quad 0..15
    int p0 = q * 4;
    int py = p0 >> 4, px0 = p0 & 15;
    const float* cp = cen + ((size_t)(b * CIN + 2 * cc) * HH + I0 + py) * WW
                      + J0 + px0;
    float4 a = *(const float4*)(cp);        // ch 2cc, 4 px
    float4 c = *(const float4*)(cp + HW);   // ch 2cc+1
    *(unsigned int*)&panel[p0][64 + 2 * cc]     = pack2(a.x, c.x);
    *(unsigned int*)&panel[p0 + 1][64 + 2 * cc] = pack2(a.y, c.y);
    *(unsigned int*)&panel[p0 + 2][64 + 2 * cc] = pack2(a.z, c.z);
    *(unsigned int*)&panel[p0 + 3][64 + 2 * cc] = pack2(a.w, c.w);
  }

  // stage xs: 10x22 halo x 32 ch; interior blocks unguarded
  {
    const bool interior = (bx >= 1 && bx <= 6 && by >= 1 && by <= 30);
    for (int idx = t; idx < 880; idx += 256) {   // 220 px x 4 segs
      int px = idx >> 2, seg = idx & 3;
      int row = px / HALOP, col = px - row * HALOP;
      int gi = I0 - 3 + row, gj = J0 - 3 + col;
      unsigned short* sp = xs + px * 36 + seg * 8;
      if (interior) {
        const unsigned short* gp = xbuf +
            ((size_t)((size_t)b * HH + gi) * WW + gj) * 32;
        uint4 v = *(const uint4*)(gp + 8 * seg);
        *(uint2*)(sp)     = make_uint2(v.x, v.y);
        *(uint2*)(sp + 4) = make_uint2(v.z, v.w);
      } else {
        bool ok = (gi >= 0 && gi < HH && gj >= 0 && gj < WW);
        const unsigned short* gp = xbuf +
            ((size_t)((size_t)b * HH + (ok ? gi : 0)) * WW + (ok ? gj : 0)) * 32;
        uint4 v = make_uint4(0u, 0u, 0u, 0u);
        if (ok) v = *(const uint4*)(gp + 8 * seg);
        *(uint2*)(sp)     = make_uint2(v.x, v.y);
        *(uint2*)(sp + 4) = make_uint2(v.z, v.w);
      }
    }
  }
  __syncthreads();

  // ---- Phase A: folded-dout 9-tap dilated conv via MFMA ----
  f32x4 acc[4];
#pragma unroll
  for (int pt = 0; pt < 4; ++pt) acc[pt] = 0.f;

  const int prow = lane & 15;           // px of the B-fragment pixel
  const int gsh = (lane >> 4) * 8;
#pragma unroll
  for (int pt = 0; pt < 4; ++pt) {      // py = pt
#pragma unroll
    for (int ty = 0; ty < 3; ++ty)
#pragma unroll
      for (int tx = 0; tx < 3; ++tx) {
        int pos = (pt + 3 * ty) * HALOP + prow + 3 * tx;
        bf16x8 bfr = *(const bf16x8*)(xs + pos * 36 + gsh);
        acc[pt] = __builtin_amdgcn_mfma_f32_16x16x32_bf16(
            af3[ty * 3 + tx], bfr, acc[pt], 0, 0, 0);
      }
  }

  // ---- Phase B: square gates (VALU); lane = pixel (py=lane>>4, px=lane&15) ----
  {
    const int py = lane >> 4, px = lane & 15;
    const int posc = (py + 3) * HALOP + (px + 3);
    int pos8[8];
    pos8[0] = (py + 0) * HALOP + px + 0;   // (-3,-3)
    pos8[1] = (py + 0) * HALOP + px + 3;   // (-3, 0)
    pos8[2] = (py + 0) * HALOP + px + 6;   // (-3, 3)
    pos8[3] = (py + 3) * HALOP + px + 6;   // ( 0, 3)
    pos8[4] = (py + 6) * HALOP + px + 6;   // ( 3, 3)
    pos8[5] = (py + 6) * HALOP + px + 3;   // ( 3, 0)
    pos8[6] = (py + 6) * HALOP + px + 0;   // ( 3,-3)
    pos8[7] = (py + 3) * HALOP + px + 0;   // ( 0,-3)

#pragma unroll
    for (int j = 0; j < 4; ++j) {
      int c2 = __builtin_amdgcn_readfirstlane(j * 4 + w);  // 0..15
      const float* w1lo = w1 + (2 * c2) * 16;       // wave-uniform (scalar)
      const float* w1hi = w1 + (2 * c2 + 1) * 16;
      const float* w2lo = w2 + (2 * c2) * 16;
      const float* w2hi = w2 + (2 * c2 + 1) * 16;
      unsigned uc = *(const unsigned*)(xs + posc * 36 + 2 * c2);
      float clo = losf(uc), chi = hisf(uc);
      float g1l0 = 0, g1l1 = 0, g2l0 = 0, g2l1 = 0;
      float g1h0 = 0, g1h1 = 0, g2h0 = 0, g2h1 = 0;
#pragma unroll
      for (int k = 0; k < 8; ++k) {
        unsigned us = *(const unsigned*)(xs + pos8[k] * 36 + 2 * c2);
        float dlo = clo - losf(us);
        float dhi = chi - hisf(us);
        g1l0 += dlo * w1lo[k];  g1l1 += dlo * w1lo[8 + k];
        g2l0 += dlo * w2lo[k];  g2l1 += dlo * w2lo[8 + k];
        g1h0 += dhi * w1hi[k];  g1h1 += dhi * w1hi[8 + k];
        g2h0 += dhi * w2hi[k];  g2h1 += dhi * w2hi[8 + k];
      }
      uint2 wv;
      wv.x = pack2(g1l0 * g2l0, g1l1 * g2l1);
      wv.y = pack2(g1h0 * g2h0, g1h1 * g2h1);
      *(uint2*)&panel[lane][4 * c2] = wv;   // sq cols 4c2..4c2+3
    }
  }
  __syncthreads();

  // ---- Phase C: final GEMM K=128 over panel (sq + cen) ----
#pragma unroll
  for (int pt = 0; pt < 4; ++pt) {
#pragma unroll
    for (int kt = 0; kt < 4; ++kt) {
      bf16x8 bfr = *(const bf16x8*)(&panel[pt * 16 + prow][kt * 32 + gsh]);
      acc[pt] = __builtin_amdgcn_mfma_f32_16x16x32_bf16(
          af2[kt], bfr, acc[pt], 0, 0, 0);
    }
  }

  // epilogue: bias + store fp32; 16 lanes x 4B = full 64B line per (o,row)
  float4 bo = *(const float4*)(b_out + w * 16 + (lane >> 4) * 4);
#pragma unroll
  for (int pt = 0; pt < 4; ++pt) {      // py = pt, px = prow
#pragma unroll
    for (int r = 0; r < 4; ++r) {
      int o = w * 16 + (lane >> 4) * 4 + r;
      out[((b * OUTC + o) * HH + I0 + pt) * WW + J0 + prow] =
          acc[pt][r] + ((const float*)&bo)[r];
    }
  }
}

// ---------------------------------------------------------------------------
extern "C" void kernel_launch(void* const* d_in, const int* in_sizes, int n_in,
                              void* d_out, int out_size, void* d_ws, size_t ws_size,
                              hipStream_t stream) {
  const float* cen   = (const float*)d_in[0];
  const float* mas   = (const float*)d_in[1];
  const float* w_inp = (const float*)d_in[2];
  const float* b_inp = (const float*)d_in[3];
  const float* w1    = (const float*)d_in[4];
  const float* w2    = (const float*)d_in[5];
  const float* w3    = (const float*)d_in[6];
  const float* w_out = (const float*)d_in[7];
  const float* b_out = (const float*)d_in[8];
  float* out = (float*)d_out;

  unsigned short* xbuf   = (unsigned short*)d_ws;            // bf16, 16.8 MB
  unsigned short* wfrag  = xbuf + (size_t)BATCH * HW * 32;   // 9216
  unsigned short* wfrag2 = wfrag + 9216;                     // 8192
  unsigned short* wfrag3 = wfrag2 + 8192;                    // 18432

  hipLaunchKernelGGL(k_prep_weights, dim3(140), dim3(256), 0, stream,
                     w_out, w_inp, w3, wfrag, wfrag2, wfrag3);
  hipLaunchKernelGGL(k_stem, dim3(4, 64, 16), dim3(256), 0, stream,
                     mas, wfrag, b_inp, xbuf);
  hipLaunchKernelGGL(k_fused, dim3(8, 32, 16), dim3(256), 0, stream,
                     xbuf, cen, w1, w2, wfrag2, wfrag3, b_out, out);
}

// Round 20
// 93.900 us; speedup vs baseline: 1.4998x; 1.0277x over previous
//
#include <hip/hip_runtime.h>
#include <hip/hip_bf16.h>

// Problem constants
#define BATCH 16
#define CH    32      // depthwise group count
#define CIN   64
#define OUTC  64
#define HH    128     // h after stride-2 stem
#define WW    128
#define HW    (HH * WW)
#define MHW   65536   // mas plane 256*256

typedef __attribute__((ext_vector_type(8))) short bf16x8;
typedef __attribute__((ext_vector_type(4))) float f32x4;

__device__ inline unsigned short bf16u(float x) {
  union { __hip_bfloat16 h; unsigned short s; } u;
  u.h = __float2bfloat16(x);
  return u.s;
}
__device__ inline unsigned int pack2(float lo, float hi) {
  return (unsigned int)bf16u(lo) | ((unsigned int)bf16u(hi) << 16);
}
__device__ inline float losf(unsigned u) { return __uint_as_float(u << 16); }
__device__ inline float hisf(unsigned u) { return __uint_as_float(u & 0xffff0000u); }

// ---------------------------------------------------------------------------
// Kernel 0: weight prep (bf16 MFMA A-fragments). Unchanged.
// ---------------------------------------------------------------------------
__global__ __launch_bounds__(256) void k_prep_weights(
    const float* __restrict__ w_out, const float* __restrict__ w_inp,
    const float* __restrict__ w3,
    unsigned short* __restrict__ wfrag, unsigned short* __restrict__ wfrag2,
    unsigned short* __restrict__ wfrag3) {
  int t = blockIdx.x * 256 + threadIdx.x;
  if (t < 9 * 2 * 64 * 8) {
    int e    = t & 7;
    int lane = (t >> 3) & 63;
    int ct   = (t >> 9) & 1;
    int tap  = t >> 10;
    int co = ct * 16 + (lane & 15);
    int ci = (lane >> 4) * 8 + e;
    wfrag[t] = bf16u(w_inp[(co * CH + ci) * 9 + tap]);
  }
  int t2 = t - 9216;
  if (t2 >= 0 && t2 < 8192) {
    int e    = t2 & 7;
    int lane = (t2 >> 3) & 63;
    int ot   = (t2 >> 9) & 3;
    int kt   = t2 >> 11;
    int o = ot * 16 + (lane & 15);
    int k = kt * 32 + (lane >> 4) * 8 + e;
    int col = (k < 64) ? k : 64 + k;   // sq block 0..63, cen block 128..191
    wfrag2[t2] = bf16u(w_out[o * 192 + col]);
  }
  int t3 = t - 17408;
  if (t3 >= 0 && t3 < 18432) {
    int e    = t3 & 7;
    int lane = (t3 >> 3) & 63;
    int ot   = (t3 >> 9) & 3;
    int tap  = t3 >> 11;
    int o = ot * 16 + (lane & 15);
    int C = (lane >> 4) * 8 + e;
    const int kmap[9] = {0, 1, 2, 7, -1, 3, 6, 5, 4};
    float v = 0.f;
    if (tap == 4) {
      for (int k = 0; k < 8; ++k)
        for (int op = 0; op < 2; ++op)
          v += w_out[o * 192 + 64 + 2 * C + op] * w3[C * 16 + op * 8 + k];
    } else {
      int k = kmap[tap];
      for (int op = 0; op < 2; ++op)
        v -= w_out[o * 192 + 64 + 2 * C + op] * w3[C * 16 + op * 8 + k];
    }
    wfrag3[t3] = bf16u(v);
  }
}

// ---------------------------------------------------------------------------
// Kernel 1 v14: single-pass stem; staging via float4 (4 cols/lane x 2 planes
// per task) -> half the global-load instruction count of v13.
// ---------------------------------------------------------------------------
__global__ __launch_bounds__(256, 6) void k_stem(
    const float* __restrict__ mas, const unsigned short* __restrict__ wfrag,
    const float* __restrict__ b_inp, unsigned short* __restrict__ xbuf) {
  __shared__ alignas(16) unsigned int xs32[325 * 18];   // 23.4 KB

  // XCD swizzle: 4096 blocks = 8 XCD x 512; b = F>>8 -> XCD k gets {2k,2k+1}
  const int W = blockIdx.x + 4 * blockIdx.y + 256 * blockIdx.z;
  const int F = (W & 7) * 512 + (W >> 3);
  const int bx = F & 3;          // col tile of 32
  const int by = (F >> 2) & 63;  // row band of 2
  const int b  = F >> 8;         // batch

  const int t  = threadIdx.x;
  const int lane = t & 63;
  const int w = t >> 6;

  const int I0 = by * 2, J0 = bx * 32;
  const int R0 = 4 * by - 1, C0 = 64 * bx - 1;

  const float* mb = mas + (size_t)b * CH * MHW;

  // ---- staging: 1280 tasks = 80 cells x 16 aligned float4 quads ----
  if (R0 >= 0) {                 // fast path: all rows valid (by >= 1)
#pragma unroll 5
    for (int idx = t; idx < 1280; idx += 256) {
      int cell = idx >> 4;
      int k    = idx & 15;       // col quad -> cols 1+4k .. 4+4k
      int r  = cell >> 4;
      int cp = cell & 15;
      const float* p = mb + (size_t)(2 * cp) * MHW +
                       (size_t)(R0 + r) * 256 + (C0 + 1 + 4 * k);
      float4 a = *(const float4*)(p);
      float4 c = *(const float4*)(p + MHW);
      int base = (r * 65 + 1 + 4 * k) * 18 + cp;
      xs32[base]          = pack2(a.x, c.x);
      xs32[base + 18]     = pack2(a.y, c.y);
      xs32[base + 36]     = pack2(a.z, c.z);
      xs32[base + 54]     = pack2(a.w, c.w);
    }
  } else {
#pragma unroll 5
    for (int idx = t; idx < 1280; idx += 256) {
      int cell = idx >> 4;
      int k    = idx & 15;
      int r  = cell >> 4;
      int cp = cell & 15;
      int gr = R0 + r;
      unsigned v0 = 0u, v1 = 0u, v2 = 0u, v3 = 0u;
      if (gr >= 0) {
        const float* p = mb + (size_t)(2 * cp) * MHW + (size_t)gr * 256 +
                         (C0 + 1 + 4 * k);
        float4 a = *(const float4*)(p);
        float4 c = *(const float4*)(p + MHW);
        v0 = pack2(a.x, c.x);
        v1 = pack2(a.y, c.y);
        v2 = pack2(a.z, c.z);
        v3 = pack2(a.w, c.w);
      }
      int base = (r * 65 + 1 + 4 * k) * 18 + cp;
      xs32[base]      = v0;
      xs32[base + 18] = v1;
      xs32[base + 36] = v2;
      xs32[base + 54] = v3;
    }
  }
  // tail: col 0 (gc = 64bx-1; invalid only for bx==0)
  if (t < 80) {
    int r = t >> 4, cp = t & 15;
    int gr = R0 + r;
    unsigned v = 0u;
    if (gr >= 0 && bx > 0) {
      const float* p = mb + (size_t)(2 * cp) * MHW + (size_t)gr * 256 + C0;
      v = pack2(p[0], p[MHW]);
    }
    xs32[(r * 65) * 18 + cp] = v;
  }
  __syncthreads();

  // ---- compute: wave (il = w>>1, h = w&1) -> 16 px x 32 co x 9 taps ----
  const int il = w >> 1, h = w & 1;
  const int jl = lane & 15;
  const int g4 = (lane >> 4) * 4;
  const int tc = h * 16 + jl;          // tile col 0..31

  f32x4 acc[2];
  acc[0] = 0.f;
  acc[1] = 0.f;

  const bf16x8* wf = (const bf16x8*)wfrag;
#pragma unroll
  for (int ky = 0; ky < 3; ++ky) {
#pragma unroll
    for (int kx = 0; kx < 3; ++kx) {
      const int tap = ky * 3 + kx;
      bf16x8 a0 = wf[(tap * 2 + 0) * 64 + lane];
      bf16x8 a1 = wf[(tap * 2 + 1) * 64 + lane];
      int pix = (2 * il + ky) * 65 + 2 * tc + kx;
      bf16x8 bfr = *(const bf16x8*)(xs32 + pix * 18 + g4);
      acc[0] = __builtin_amdgcn_mfma_f32_16x16x32_bf16(a0, bfr, acc[0], 0, 0, 0);
      acc[1] = __builtin_amdgcn_mfma_f32_16x16x32_bf16(a1, bfr, acc[1], 0, 0, 0);
    }
  }

  // ---- epilogue: bias + SiLU, store bf16 channel-interleaved ----
  float4 bia[2];
  bia[0] = *(const float4*)(b_inp + (lane >> 4) * 4);
  bia[1] = *(const float4*)(b_inp + 16 + (lane >> 4) * 4);
  const int colg = J0 + tc;
  const int i = I0 + il;
#pragma unroll
  for (int ct = 0; ct < 2; ++ct) {
    int co0 = ct * 16 + (lane >> 4) * 4;
    float y0 = acc[ct][0] + ((const float*)&bia[ct])[0];
    float y1 = acc[ct][1] + ((const float*)&bia[ct])[1];
    float y2 = acc[ct][2] + ((const float*)&bia[ct])[2];
    float y3 = acc[ct][3] + ((const float*)&bia[ct])[3];
    float s0 = y0 / (1.f + __expf(-y0));
    float s1 = y1 / (1.f + __expf(-y1));
    float s2 = y2 / (1.f + __expf(-y2));
    float s3 = y3 / (1.f + __expf(-y3));
    uint2 uv;
    uv.x = pack2(s0, s1);
    uv.y = pack2(s2, s3);
    *(uint2*)(xbuf + ((size_t)(b * HH + i) * WW + colg) * 32 + co0) = uv;
  }
}

// ---------------------------------------------------------------------------
// Kernel 2 v6: 4x16 tile (R19) + T14 cen staging split: cen loaded to
// REGISTERS before barrier 1 (latency hides under Phase A/B), written to
// panel after Phase B, just before barrier 2.
// ---------------------------------------------------------------------------
#define PPITCH 132
#define HALOP 22

__global__ __launch_bounds__(256, 4) void k_fused(
    const unsigned short* __restrict__ xbuf, const float* __restrict__ cen,
    const float* __restrict__ w1, const float* __restrict__ w2,
    const unsigned short* __restrict__ wfrag2,
    const unsigned short* __restrict__ wfrag3,
    const float* __restrict__ b_out, float* __restrict__ out) {
  __shared__ alignas(16) unsigned short xs[220 * 36];      // 15.5 KB
  __shared__ alignas(16) unsigned short panel[64][PPITCH]; // 16.9 KB

  // XCD swizzle: 4096 blocks = 8 XCD x 512; b = F>>8
  const int W = blockIdx.x + 8 * blockIdx.y + 256 * blockIdx.z;
  const int F = (W & 7) * 512 + (W >> 3);
  const int bx = F & 7;          // x tile of 16
  const int by = (F >> 3) & 31;  // y tile of 4
  const int b  = F >> 8;

  const int t  = threadIdx.x;
  const int lane = t & 63;
  const int w = t >> 6;
  const int I0 = by * 4, J0 = bx * 16;

  bf16x8 af3[9], af2[4];
#pragma unroll
  for (int tap = 0; tap < 9; ++tap)
    af3[tap] = ((const bf16x8*)wfrag3)[(tap * 4 + w) * 64 + lane];
#pragma unroll
  for (int kt = 0; kt < 4; ++kt)
    af2[kt] = ((const bf16x8*)wfrag2)[(kt * 4 + w) * 64 + lane];

  // T14 split part 1: ISSUE cen loads into registers (no LDS write yet).
  // 512 tasks: idx = j*256+t -> cc = idx>>4 (ch pair), q = idx&15 (px quad)
  float4 cenA[2], cenC[2];
#pragma unroll
  for (int j = 0; j < 2; ++j) {
    int idx = j * 256 + t;
    int cc = idx >> 4;
    int q  = idx & 15;
    int p0 = q * 4;
    int py = p0 >> 4, px0 = p0 & 15;
    const float* cp = cen + ((size_t)(b * CIN + 2 * cc) * HH + I0 + py) * WW
                      + J0 + px0;
    cenA[j] = *(const float4*)(cp);        // ch 2cc, 4 px
    cenC[j] = *(const float4*)(cp + HW);   // ch 2cc+1
  }

  // stage xs: 10x22 halo x 32 ch; interior blocks unguarded
  {
    const bool interior = (bx >= 1 && bx <= 6 && by >= 1 && by <= 30);
    for (int idx = t; idx < 880; idx += 256) {   // 220 px x 4 segs
      int px = idx >> 2, seg = idx & 3;
      int row = px / HALOP, col = px - row * HALOP;
      int gi = I0 - 3 + row, gj = J0 - 3 + col;
      unsigned short* sp = xs + px * 36 + seg * 8;
      if (interior) {
        const unsigned short* gp = xbuf +
            ((size_t)((size_t)b * HH + gi) * WW + gj) * 32;
        uint4 v = *(const uint4*)(gp + 8 * seg);
        *(uint2*)(sp)     = make_uint2(v.x, v.y);
        *(uint2*)(sp + 4) = make_uint2(v.z, v.w);
      } else {
        bool ok = (gi >= 0 && gi < HH && gj >= 0 && gj < WW);
        const unsigned short* gp = xbuf +
            ((size_t)((size_t)b * HH + (ok ? gi : 0)) * WW + (ok ? gj : 0)) * 32;
        uint4 v = make_uint4(0u, 0u, 0u, 0u);
        if (ok) v = *(const uint4*)(gp + 8 * seg);
        *(uint2*)(sp)     = make_uint2(v.x, v.y);
        *(uint2*)(sp + 4) = make_uint2(v.z, v.w);
      }
    }
  }
  __syncthreads();

  // ---- Phase A: folded-dout 9-tap dilated conv via MFMA ----
  f32x4 acc[4];
#pragma unroll
  for (int pt = 0; pt < 4; ++pt) acc[pt] = 0.f;

  const int prow = lane & 15;           // px of the B-fragment pixel
  const int gsh = (lane >> 4) * 8;
#pragma unroll
  for (int pt = 0; pt < 4; ++pt) {      // py = pt
#pragma unroll
    for (int ty = 0; ty < 3; ++ty)
#pragma unroll
      for (int tx = 0; tx < 3; ++tx) {
        int pos = (pt + 3 * ty) * HALOP + prow + 3 * tx;
        bf16x8 bfr = *(const bf16x8*)(xs + pos * 36 + gsh);
        acc[pt] = __builtin_amdgcn_mfma_f32_16x16x32_bf16(
            af3[ty * 3 + tx], bfr, acc[pt], 0, 0, 0);
      }
  }

  // ---- Phase B: square gates (VALU); lane = pixel (py=lane>>4, px=lane&15) ----
  {
    const int py = lane >> 4, px = lane & 15;
    const int posc = (py + 3) * HALOP + (px + 3);
    int pos8[8];
    pos8[0] = (py + 0) * HALOP + px + 0;   // (-3,-3)
    pos8[1] = (py + 0) * HALOP + px + 3;   // (-3, 0)
    pos8[2] = (py + 0) * HALOP + px + 6;   // (-3, 3)
    pos8[3] = (py + 3) * HALOP + px + 6;   // ( 0, 3)
    pos8[4] = (py + 6) * HALOP + px + 6;   // ( 3, 3)
    pos8[5] = (py + 6) * HALOP + px + 3;   // ( 3, 0)
    pos8[6] = (py + 6) * HALOP + px + 0;   // ( 3,-3)
    pos8[7] = (py + 3) * HALOP + px + 0;   // ( 0,-3)

#pragma unroll
    for (int j = 0; j < 4; ++j) {
      int c2 = __builtin_amdgcn_readfirstlane(j * 4 + w);  // 0..15
      const float* w1lo = w1 + (2 * c2) * 16;       // wave-uniform (scalar)
      const float* w1hi = w1 + (2 * c2 + 1) * 16;
      const float* w2lo = w2 + (2 * c2) * 16;
      const float* w2hi = w2 + (2 * c2 + 1) * 16;
      unsigned uc = *(const unsigned*)(xs + posc * 36 + 2 * c2);
      float clo = losf(uc), chi = hisf(uc);
      float g1l0 = 0, g1l1 = 0, g2l0 = 0, g2l1 = 0;
      float g1h0 = 0, g1h1 = 0, g2h0 = 0, g2h1 = 0;
#pragma unroll
      for (int k = 0; k < 8; ++k) {
        unsigned us = *(const unsigned*)(xs + pos8[k] * 36 + 2 * c2);
        float dlo = clo - losf(us);
        float dhi = chi - hisf(us);
        g1l0 += dlo * w1lo[k];  g1l1 += dlo * w1lo[8 + k];
        g2l0 += dlo * w2lo[k];  g2l1 += dlo * w2lo[8 + k];
        g1h0 += dhi * w1hi[k];  g1h1 += dhi * w1hi[8 + k];
        g2h0 += dhi * w2hi[k];  g2h1 += dhi * w2hi[8 + k];
      }
      uint2 wv;
      wv.x = pack2(g1l0 * g2l0, g1l1 * g2l1);
      wv.y = pack2(g1h0 * g2h0, g1h1 * g2h1);
      *(uint2*)&panel[lane][4 * c2] = wv;   // sq cols 4c2..4c2+3
    }
  }

  // T14 split part 2: write cen registers -> panel (loads long since landed)
#pragma unroll
  for (int j = 0; j < 2; ++j) {
    int idx = j * 256 + t;
    int cc = idx >> 4;
    int q  = idx & 15;
    int p0 = q * 4;
    *(unsigned int*)&panel[p0][64 + 2 * cc]     = pack2(cenA[j].x, cenC[j].x);
    *(unsigned int*)&panel[p0 + 1][64 + 2 * cc] = pack2(cenA[j].y, cenC[j].y);
    *(unsigned int*)&panel[p0 + 2][64 + 2 * cc] = pack2(cenA[j].z, cenC[j].z);
    *(unsigned int*)&panel[p0 + 3][64 + 2 * cc] = pack2(cenA[j].w, cenC[j].w);
  }
  __syncthreads();

  // ---- Phase C: final GEMM K=128 over panel (sq + cen) ----
#pragma unroll
  for (int pt = 0; pt < 4; ++pt) {
#pragma unroll
    for (int kt = 0; kt < 4; ++kt) {
      bf16x8 bfr = *(const bf16x8*)(&panel[pt * 16 + prow][kt * 32 + gsh]);
      acc[pt] = __builtin_amdgcn_mfma_f32_16x16x32_bf16(
          af2[kt], bfr, acc[pt], 0, 0, 0);
    }
  }

  // epilogue: bias + store fp32; 16 lanes x 4B = full 64B line per (o,row)
  float4 bo = *(const float4*)(b_out + w * 16 + (lane >> 4) * 4);
#pragma unroll
  for (int pt = 0; pt < 4; ++pt) {      // py = pt, px = prow
#pragma unroll
    for (int r = 0; r < 4; ++r) {
      int o = w * 16 + (lane >> 4) * 4 + r;
      out[((b * OUTC + o) * HH + I0 + pt) * WW + J0 + prow] =
          acc[pt][r] + ((const float*)&bo)[r];
    }
  }
}

// ---------------------------------------------------------------------------
extern "C" void kernel_launch(void* const* d_in, const int* in_sizes, int n_in,
                              void* d_out, int out_size, void* d_ws, size_t ws_size,
                              hipStream_t stream) {
  const float* cen   = (const float*)d_in[0];
  const float* mas   = (const float*)d_in[1];
  const float* w_inp = (const float*)d_in[2];
  const float* b_inp = (const float*)d_in[3];
  const float* w1    = (const float*)d_in[4];
  const float* w2    = (const float*)d_in[5];
  const float* w3    = (const float*)d_in[6];
  const float* w_out = (const float*)d_in[7];
  const float* b_out = (const float*)d_in[8];
  float* out = (float*)d_out;

  unsigned short* xbuf   = (unsigned short*)d_ws;            // bf16, 16.8 MB
  unsigned short* wfrag  = xbuf + (size_t)BATCH * HW * 32;   // 9216
  unsigned short* wfrag2 = wfrag + 9216;                     // 8192
  unsigned short* wfrag3 = wfrag2 + 8192;                    // 18432

  hipLaunchKernelGGL(k_prep_weights, dim3(140), dim3(256), 0, stream,
                     w_out, w_inp, w3, wfrag, wfrag2, wfrag3);
  hipLaunchKernelGGL(k_stem, dim3(4, 64, 16), dim3(256), 0, stream,
                     mas, wfrag, b_inp, xbuf);
  hipLaunchKernelGGL(k_fused, dim3(8, 32, 16), dim3(256), 0, stream,
                     xbuf, cen, w1, w2, wfrag2, wfrag3, b_out, out);
}